// Round 17
// baseline (2019.383 us; speedup 1.0000x reference)
//
#include <hip/hip_runtime.h>
#include <math.h>

constexpr int NB = 8;      // batch
constexpr int NN = 2048;   // points
constexpr int NK = 20;     // knn
constexpr int NP = 2048;   // decoder points

// ---------------- utils ----------------

__global__ void transpose_x_kernel(const float* __restrict__ x, float* __restrict__ pts) {
  int gid = blockIdx.x * 256 + threadIdx.x;  // over B*N*3 outputs [b][n][c]
  if (gid >= NB * NN * 3) return;
  int c = gid % 3;
  int n = (gid / 3) % NN;
  int b = gid / (3 * NN);
  pts[gid] = x[(b * 3 + c) * NN + n];
}

// dst[c*ldd + r] = src[r*C + c]
__global__ void transpose_mat_ld(const float* __restrict__ src, float* __restrict__ dst, int R,
                                 int C, int ldd) {
  __shared__ float tile[32][33];
  int c0 = blockIdx.x * 32, r0 = blockIdx.y * 32;
  int tx = threadIdx.x & 31, ty = threadIdx.x >> 5;  // 32 x 8
  for (int i = ty; i < 32; i += 8) {
    int r = r0 + i, c = c0 + tx;
    tile[i][tx] = (r < R && c < C) ? src[(size_t)r * C + c] : 0.f;
  }
  __syncthreads();
  for (int i = ty; i < 32; i += 8) {
    int c = c0 + i, r = r0 + tx;
    if (r < R && c < C) dst[(size_t)c * ldd + r] = tile[tx][i];
  }
}

// ---------------- KNN layer 1 (D=3): fused dist + top-20 ----------------
__global__ void knn3_fused_kernel(const float* __restrict__ pts, int* __restrict__ idx) {
  __shared__ float sm[3][NN];  // [dim][col]
  int t = threadIdx.x;
  int l = t & 63, w = t >> 6;
  int gb = blockIdx.x;    // over B*NN/4
  int b = gb >> 9;        // 512 blocks per batch
  int n0 = (gb & 511) * 4;
  const float* base = pts + (size_t)b * NN * 3;
  for (int e = t; e < NN * 3; e += 256) {
    int col = e / 3, d = e - col * 3;
    sm[d][col] = base[e];
  }
  __syncthreads();
  int n = n0 + w;
  float c0 = sm[0][n], c1 = sm[1][n], c2 = sm[2][n];
  float v[32];
#pragma unroll
  for (int j = 0; j < 32; j++) {
    int col = j * 64 + l;
    float d0 = c0 - sm[0][col];
    float d1 = c1 - sm[1][col];
    float d2 = c2 - sm[2][col];
    float acc = 0.f;
    acc = fmaf(d0, d0, acc);
    acc = fmaf(d1, d1, acc);
    acc = fmaf(d2, d2, acc);
    v[j] = -acc;
  }
  int mykm = 0;
  for (int k = 0; k < NK; k++) {
    float bv = v[0];
    int bj = 0;
#pragma unroll
    for (int j = 1; j < 32; j++) {
      if (v[j] > bv) { bv = v[j]; bj = j; }
    }
    int gm = bj * 64 + l;
#pragma unroll
    for (int off = 32; off; off >>= 1) {
      float ov = __shfl_xor(bv, off, 64);
      int om = __shfl_xor(gm, off, 64);
      if (ov > bv || (ov == bv && om < gm)) { bv = ov; gm = om; }
    }
    if (l == k) mykm = gm;
    int jb = gm >> 6, lb = gm & 63;
#pragma unroll
    for (int j = 0; j < 32; j++)
      if (j == jb && l == lb) v[j] = -3e38f;
  }
  if (l < NK) idx[((size_t)(b * NN + n)) * NK + l] = mykm;
}

// ---------------- KNN D=64: fused dist + top-20, 4 centers/wave ----------------
// 256-thread block (4 waves) owns 16 center rows; wave w owns centers
// n0+4w..n0+4w+3. Features stream through LDS in 16 transposed 128-col tiles.
// Per d: two conflict-free scalar reads (cols l and 64+l) amortized over 4
// centers (16 fma) -> 4x less LDS traffic than 1-center/wave. Distance values
// are bit-identical to the two-phase path (same fmaf chain, d ascending).
// Slot j of lane l holds col (j>>1)*128 + (j&1)*64 + l  (ascending in j).
__global__ __launch_bounds__(256, 2) void knn64_fused4_kernel(const float* __restrict__ h, int ld,
                                                              int coff, int* __restrict__ idx) {
  __shared__ float sft[64][128];  // feature tile [dim][col_local]
  __shared__ float sctr[16][64];  // 16 center rows
  int t = threadIdx.x;
  int l = t & 63, w = t >> 6;  // wave 0..3
  int n0 = blockIdx.x * 16;
  int b = blockIdx.y;
  const float* rows = h + (size_t)b * NN * ld + coff;
  for (int e = t; e < 16 * 64; e += 256) {
    int r = e >> 6, d = e & 63;
    sctr[r][d] = rows[(size_t)(n0 + r) * ld + d];
  }
  int colg = t & 127;
  int dh = (t >> 7) * 32;
  float v[4][32];
#pragma unroll
  for (int ct = 0; ct < 16; ct++) {
    __syncthreads();
    {
      const float* src = &rows[(size_t)(ct * 128 + colg) * ld + dh];
#pragma unroll
      for (int q = 0; q < 8; q++) {
        float4 f = *(const float4*)(src + q * 4);
        sft[dh + q * 4 + 0][colg] = f.x;
        sft[dh + q * 4 + 1][colg] = f.y;
        sft[dh + q * 4 + 2][colg] = f.z;
        sft[dh + q * 4 + 3][colg] = f.w;
      }
    }
    __syncthreads();
    float a00 = 0.f, a01 = 0.f, a10 = 0.f, a11 = 0.f;
    float a20 = 0.f, a21 = 0.f, a30 = 0.f, a31 = 0.f;
#pragma unroll 8
    for (int d = 0; d < 64; d++) {
      float f0 = sft[d][l];        // lane-stride 1 -> conflict-free
      float f1 = sft[d][64 + l];   // lane-stride 1 -> conflict-free
      float c0v = sctr[4 * w + 0][d];  // wave-uniform broadcasts
      float c1v = sctr[4 * w + 1][d];
      float c2v = sctr[4 * w + 2][d];
      float c3v = sctr[4 * w + 3][d];
      float e;
      e = c0v - f0; a00 = fmaf(e, e, a00);
      e = c0v - f1; a01 = fmaf(e, e, a01);
      e = c1v - f0; a10 = fmaf(e, e, a10);
      e = c1v - f1; a11 = fmaf(e, e, a11);
      e = c2v - f0; a20 = fmaf(e, e, a20);
      e = c2v - f1; a21 = fmaf(e, e, a21);
      e = c3v - f0; a30 = fmaf(e, e, a30);
      e = c3v - f1; a31 = fmaf(e, e, a31);
    }
    v[0][2 * ct] = -a00; v[0][2 * ct + 1] = -a01;
    v[1][2 * ct] = -a10; v[1][2 * ct + 1] = -a11;
    v[2][2 * ct] = -a20; v[2][2 * ct + 1] = -a21;
    v[3][2 * ct] = -a30; v[3][2 * ct + 1] = -a31;
  }
#pragma unroll
  for (int ci = 0; ci < 4; ci++) {
    int mykm = 0;
    for (int k = 0; k < NK; k++) {
      float bv = v[ci][0];
      int bj = 0;
#pragma unroll
      for (int j = 1; j < 32; j++) {
        if (v[ci][j] > bv) { bv = v[ci][j]; bj = j; }  // strict >: smallest col in-lane
      }
      int gm = ((bj >> 1) << 7) + ((bj & 1) << 6) + l;
#pragma unroll
      for (int off = 32; off; off >>= 1) {
        float ov = __shfl_xor(bv, off, 64);
        int om = __shfl_xor(gm, off, 64);
        if (ov > bv || (ov == bv && om < gm)) { bv = ov; gm = om; }
      }
      if (l == k) mykm = gm;
      int jb = ((gm >> 7) << 1) + ((gm >> 6) & 1);
      int lb = gm & 63;
#pragma unroll
      for (int j = 0; j < 32; j++)
        if (j == jb && l == lb) v[ci][j] = -3e38f;
    }
    if (l < NK) idx[((size_t)(b * NN + n0 + 4 * w + ci)) * NK + l] = mykm;
  }
}

// ---------------- Edge conv factorized: Weff, pgemm, combine ----------------
__global__ void weff_kernel(const float* __restrict__ W, int O, int D, float* __restrict__ Weff) {
  int i = blockIdx.x * 256 + threadIdx.x;  // over 2O*D
  if (i >= 2 * O * D) return;
  int o = i / D, d = i - o * D;
  float v;
  if (o < O) v = W[(size_t)o * 2 * D + d] - W[(size_t)o * 2 * D + D + d];
  else v = W[(size_t)(o - O) * 2 * D + D + d];
  Weff[i] = v;
}

// P[n][0..O) = bias + Weff[0..O) . h[n]; P[n][O..2O) = Weff[O..) . h[n]
template <int M2, int D>
__global__ __launch_bounds__(256, 4) void pgemm_kernel(const float* __restrict__ h, int ld,
                                                       int coff, const float* __restrict__ Weff,
                                                       const float* __restrict__ bias,
                                                       float* __restrict__ P) {
  constexpr int O = M2 / 2;
  constexpr int GRP = 256 / M2;  // 2 or 1
  constexpr int NR = 8 / GRP;    // 4 or 8
  __shared__ float sh[8][D == 3 ? 4 : 68];
  int t = threadIdx.x;
  int n0 = blockIdx.x * 8;
  const float* base = h + coff;
  if constexpr (D == 64) {
    if (t < 128) {
      int r = t >> 4, q = (t & 15) * 4;
      *(float4*)&sh[r][q] = *(const float4*)&base[(size_t)(n0 + r) * ld + q];
    }
  } else {
    if (t < 24) {
      int r = t / 3, c = t - r * 3;
      sh[r][c] = base[(size_t)(n0 + r) * ld + c];
    }
  }
  __syncthreads();
  int o = t % M2;
  int gi = t / M2;
  float acc[NR];
  float bz = (o < O) ? bias[o] : 0.f;
#pragma unroll
  for (int j = 0; j < NR; j++) acc[j] = bz;
  const float* wr = Weff + (size_t)o * D;
  if constexpr (D == 64) {
#pragma unroll
    for (int d4 = 0; d4 < 16; d4++) {
      float4 w4 = *(const float4*)&wr[d4 * 4];
#pragma unroll
      for (int j = 0; j < NR; j++) {
        float4 e4 = *(const float4*)&sh[gi * NR + j][d4 * 4];
        acc[j] = fmaf(w4.x, e4.x, acc[j]);
        acc[j] = fmaf(w4.y, e4.y, acc[j]);
        acc[j] = fmaf(w4.z, e4.z, acc[j]);
        acc[j] = fmaf(w4.w, e4.w, acc[j]);
      }
    }
  } else {
    float w0 = wr[0], w1 = wr[1], w2 = wr[2];
#pragma unroll
    for (int j = 0; j < NR; j++) {
      int r = gi * NR + j;
      acc[j] = fmaf(w0, sh[r][0], fmaf(w1, sh[r][1], fmaf(w2, sh[r][2], acc[j])));
    }
  }
#pragma unroll
  for (int j = 0; j < NR; j++)
    P[(size_t)(n0 + gi * NR + j) * M2 + o] = acc[j];
}

// z[n,k,o] = relu(P1[n][o] + P2[idx[n,k]][o]); track max/min over k + f32 sum/sumsq
template <int O>
__global__ __launch_bounds__(256, 8) void combine_kernel(const float* __restrict__ P,
                                                         const int* __restrict__ idx,
                                                         float* __restrict__ zmax,
                                                         float* __restrict__ zmin,
                                                         float* __restrict__ psum,
                                                         float* __restrict__ psq) {
  constexpr int CPB = 256 / O;
  constexpr int M2 = 2 * O;
  __shared__ int sidx[CPB * NK];
  int t = threadIdx.x;
  int bn0 = blockIdx.x * CPB;
  if (t < CPB * NK) sidx[t] = idx[(size_t)bn0 * NK + t];
  __syncthreads();
  int g = t / O, o = t % O;
  int bn = bn0 + g;
  int b = bn >> 11;
  float p1 = P[(size_t)bn * M2 + o];
  const float* P2 = P + (size_t)b * NN * M2 + O + o;
  float s = 0.f, sq = 0.f, mx = -3e38f, mn = 3e38f;
#pragma unroll
  for (int k = 0; k < NK; k++) {
    int nb = sidx[g * NK + k];
    float z = fmaxf(p1 + P2[(size_t)nb * M2], 0.f);
    s += z;
    sq = fmaf(z, z, sq);
    mx = fmaxf(mx, z);
    mn = fminf(mn, z);
  }
  zmax[(size_t)bn * O + o] = mx;
  zmin[(size_t)bn * O + o] = mn;
  psum[(size_t)o * (NB * NN) + bn] = s;
  psq[(size_t)o * (NB * NN) + bn] = sq;
}

__global__ void edge_reduce_kernel(const float* __restrict__ psum, const float* __restrict__ psq,
                                   const float* __restrict__ g, const float* __restrict__ be,
                                   float* __restrict__ scale, float* __restrict__ shift,
                                   double inv_n) {
  int o = blockIdx.x, t = threadIdx.x;
  double s = 0.0, q = 0.0;
  const float* ps = psum + (size_t)o * (NB * NN);
  const float* pq = psq + (size_t)o * (NB * NN);
  for (int i = t; i < NB * NN; i += 256) { s += (double)ps[i]; q += (double)pq[i]; }
  __shared__ double rs[256], rq[256];
  rs[t] = s; rq[t] = q;
  __syncthreads();
  for (int st = 128; st; st >>= 1) {
    if (t < st) { rs[t] += rs[t + st]; rq[t] += rq[t + st]; }
    __syncthreads();
  }
  if (t == 0) {
    double mean = rs[0] * inv_n;
    double var = rq[0] * inv_n - mean * mean;
    double r = 1.0 / sqrt(var + 1e-5);
    double sc = (double)g[o] * r;
    scale[o] = (float)sc;
    shift[o] = (float)((double)be[o] - mean * sc);
  }
}

__global__ void edge_affine_kernel(const float* __restrict__ zmax, const float* __restrict__ zmin,
                                   const float* __restrict__ scale, const float* __restrict__ shift,
                                   float* __restrict__ cat, int O, int coff_out) {
  int gid = blockIdx.x * 256 + threadIdx.x;  // over B*N*O
  int o = gid % O;
  int bn = gid / O;
  float sc = scale[o];
  float v = (sc >= 0.f) ? zmax[gid] : zmin[gid];
  cat[(size_t)bn * 320 + coff_out + o] = fmaf(sc, v, shift[o]);
}

// ---------------- W5 GEMM (64x128 tile, 4x8/thread, KSTEP=32) ----------------
__global__ __launch_bounds__(256, 2) void gemm5_64_kernel(const float* __restrict__ cat,
                                                          const float* __restrict__ W5t,
                                                          const float* __restrict__ b5,
                                                          float* __restrict__ z5) {
  __shared__ float sA[32][64];   // [c][row]
  __shared__ float sB[32][128];  // [c][m]
  int t = threadIdx.x;
  int r0 = blockIdx.x * 64, m0 = blockIdx.y * 128;
  int arow = t & 63, ach = (t >> 6) * 8;   // A: row, 8 c's
  int blr = t >> 4, blc = (t & 15) * 8;    // B: c in [0,16), 8 m's
  int tx = t & 15, ty = t >> 4;
  float acc[4][8] = {};
  float rA[8], rB[16];

  auto gload = [&](int c0) {
    const float* pa = &cat[(size_t)(r0 + arow) * 320 + c0 + ach];
    float4 a0 = *(const float4*)pa;
    float4 a1 = *(const float4*)(pa + 4);
    rA[0] = a0.x; rA[1] = a0.y; rA[2] = a0.z; rA[3] = a0.w;
    rA[4] = a1.x; rA[5] = a1.y; rA[6] = a1.z; rA[7] = a1.w;
    const float* pb = &W5t[(size_t)(c0 + blr) * 1024 + m0 + blc];
    float4 b0 = *(const float4*)pb;
    float4 b1 = *(const float4*)(pb + 4);
    rB[0] = b0.x; rB[1] = b0.y; rB[2] = b0.z; rB[3] = b0.w;
    rB[4] = b1.x; rB[5] = b1.y; rB[6] = b1.z; rB[7] = b1.w;
    const float* pb2 = &W5t[(size_t)(c0 + 16 + blr) * 1024 + m0 + blc];
    float4 c4 = *(const float4*)pb2;
    float4 c5 = *(const float4*)(pb2 + 4);
    rB[8] = c4.x; rB[9] = c4.y; rB[10] = c4.z; rB[11] = c4.w;
    rB[12] = c5.x; rB[13] = c5.y; rB[14] = c5.z; rB[15] = c5.w;
  };
  auto ldswrite = [&]() {
#pragma unroll
    for (int j = 0; j < 8; j++) sA[ach + j][arow] = rA[j];
    float4 w0, w1;
    w0.x = rB[0]; w0.y = rB[1]; w0.z = rB[2]; w0.w = rB[3];
    w1.x = rB[4]; w1.y = rB[5]; w1.z = rB[6]; w1.w = rB[7];
    *(float4*)&sB[blr][blc] = w0;
    *(float4*)&sB[blr][blc + 4] = w1;
    w0.x = rB[8]; w0.y = rB[9]; w0.z = rB[10]; w0.w = rB[11];
    w1.x = rB[12]; w1.y = rB[13]; w1.z = rB[14]; w1.w = rB[15];
    *(float4*)&sB[16 + blr][blc] = w0;
    *(float4*)&sB[16 + blr][blc + 4] = w1;
  };

  gload(0);
  for (int kt = 0; kt < 10; kt++) {
    __syncthreads();
    ldswrite();
    __syncthreads();
    if (kt + 1 < 10) gload((kt + 1) * 32);
#pragma unroll
    for (int c = 0; c < 32; c++) {
      float4 a0 = *(const float4*)&sA[c][ty * 4];
      float4 b0 = *(const float4*)&sB[c][tx * 4];
      float4 b1 = *(const float4*)&sB[c][64 + tx * 4];
      float av[4] = {a0.x, a0.y, a0.z, a0.w};
      float bv[8] = {b0.x, b0.y, b0.z, b0.w, b1.x, b1.y, b1.z, b1.w};
#pragma unroll
      for (int i = 0; i < 4; i++)
#pragma unroll
        for (int j = 0; j < 8; j++) acc[i][j] = fmaf(av[i], bv[j], acc[i][j]);
    }
  }
  float bj[8];
#pragma unroll
  for (int j = 0; j < 8; j++)
    bj[j] = b5[m0 + (j < 4 ? tx * 4 + j : 64 + tx * 4 + (j - 4))];
#pragma unroll
  for (int i = 0; i < 4; i++) {
    int r = r0 + ty * 4 + i;
    float* dst = &z5[(size_t)r * 1024 + m0];
    float4 q0, q1;
    q0.x = fmaxf(acc[i][0] + bj[0], 0.f);
    q0.y = fmaxf(acc[i][1] + bj[1], 0.f);
    q0.z = fmaxf(acc[i][2] + bj[2], 0.f);
    q0.w = fmaxf(acc[i][3] + bj[3], 0.f);
    q1.x = fmaxf(acc[i][4] + bj[4], 0.f);
    q1.y = fmaxf(acc[i][5] + bj[5], 0.f);
    q1.z = fmaxf(acc[i][6] + bj[6], 0.f);
    q1.w = fmaxf(acc[i][7] + bj[7], 0.f);
    *(float4*)&dst[tx * 4] = q0;
    *(float4*)&dst[64 + tx * 4] = q1;
  }
}

__global__ void stats5_kernel(const float* __restrict__ z5, double* __restrict__ psum5,
                              double* __restrict__ psq5, float* __restrict__ pmax5,
                              float* __restrict__ pmin5) {
  int j = blockIdx.x, t = threadIdx.x;
  int row0 = j * 64;
  double s0 = 0, s1 = 0, s2 = 0, s3 = 0, q0 = 0, q1 = 0, q2 = 0, q3 = 0;
  float4 mx = {-3e38f, -3e38f, -3e38f, -3e38f}, mn = {3e38f, 3e38f, 3e38f, 3e38f};
  for (int r = 0; r < 64; r++) {
    float4 v = *(const float4*)&z5[(size_t)(row0 + r) * 1024 + t * 4];
    s0 += v.x; s1 += v.y; s2 += v.z; s3 += v.w;
    q0 += (double)v.x * v.x; q1 += (double)v.y * v.y;
    q2 += (double)v.z * v.z; q3 += (double)v.w * v.w;
    mx.x = fmaxf(mx.x, v.x); mx.y = fmaxf(mx.y, v.y); mx.z = fmaxf(mx.z, v.z); mx.w = fmaxf(mx.w, v.w);
    mn.x = fminf(mn.x, v.x); mn.y = fminf(mn.y, v.y); mn.z = fminf(mn.z, v.z); mn.w = fminf(mn.w, v.w);
  }
  size_t base = (size_t)j * 1024 + t * 4;
  psum5[base + 0] = s0; psum5[base + 1] = s1; psum5[base + 2] = s2; psum5[base + 3] = s3;
  psq5[base + 0] = q0; psq5[base + 1] = q1; psq5[base + 2] = q2; psq5[base + 3] = q3;
  *(float4*)&pmax5[base] = mx;
  *(float4*)&pmin5[base] = mn;
}

__global__ void reduce5_glob_kernel(const double* __restrict__ psum5, const double* __restrict__ psq5,
                                    const float* __restrict__ pmax5, const float* __restrict__ pmin5,
                                    const float* __restrict__ g5, const float* __restrict__ be5,
                                    float* __restrict__ glob) {
  int o = blockIdx.x * 256 + threadIdx.x;
  double s = 0.0, q = 0.0;
  for (int j = 0; j < 256; j++) {
    s += psum5[(size_t)j * 1024 + o];
    q += psq5[(size_t)j * 1024 + o];
  }
  double mean = s * (1.0 / 16384.0);
  double var = q * (1.0 / 16384.0) - mean * mean;
  double r = 1.0 / sqrt(var + 1e-5);
  double scd = (double)g5[o] * r;
  float sc = (float)scd;
  float sh = (float)((double)be5[o] - mean * scd);
  for (int b = 0; b < 8; b++) {
    float m;
    if (sc >= 0.f) {
      m = -3e38f;
      for (int jj = 0; jj < 32; jj++) m = fmaxf(m, pmax5[(size_t)(b * 32 + jj) * 1024 + o]);
    } else {
      m = 3e38f;
      for (int jj = 0; jj < 32; jj++) m = fminf(m, pmin5[(size_t)(b * 32 + jj) * 1024 + o]);
    }
    glob[b * 1024 + o] = fmaf(sc, m, sh);
  }
}

// ---------------- fully-connected helper (o-tiled, 8-way c-split) ----------------
__global__ void fc_kernel(const float* __restrict__ in, const float* __restrict__ Wt, int ld,
                          int coff, const float* __restrict__ bias, float* __restrict__ out,
                          int Ci, int Co) {
  __shared__ float sin_[1024];
  __shared__ float red[8][32];
  int b = blockIdx.x, t = threadIdx.x;
  for (int e = t; e < Ci; e += 256) sin_[e] = in[(size_t)b * Ci + e];
  __syncthreads();
  int o = blockIdx.y * 32 + (t & 31);
  int cg = t >> 5;
  int cn = Ci / 8;
  float p = 0.f;
  if (o < Co) {
    for (int c = cg * cn; c < (cg + 1) * cn; c++)
      p = fmaf(Wt[(size_t)(c + coff) * ld + o], sin_[c], p);
  }
  red[cg][t & 31] = p;
  __syncthreads();
  if (cg == 0 && o < Co) {
    float s = red[0][t] + red[1][t] + red[2][t] + red[3][t] + red[4][t] + red[5][t] + red[6][t] +
              red[7][t];
    out[(size_t)b * Co + o] = s + bias[o];
  }
}

__global__ void lat_bn_kernel(const float* __restrict__ latp, const float* __restrict__ lg,
                              const float* __restrict__ lbe, float* __restrict__ lat) {
  int o = blockIdx.x * 256 + threadIdx.x;
  float v[8];
  double s = 0.0, q = 0.0;
  for (int b = 0; b < 8; b++) {
    v[b] = latp[b * 1024 + o];
    s += (double)v[b];
    q += (double)v[b] * (double)v[b];
  }
  double mean = s * 0.125;
  double var = q * 0.125 - mean * mean;
  double r = 1.0 / sqrt(var + 1e-5);
  double gd = (double)lg[o], bd = (double)lbe[o];
  for (int b = 0; b < 8; b++) {
    float z = (float)(((double)v[b] - mean) * r * gd + bd);
    lat[b * 1024 + o] = fmaxf(z, 0.f);
  }
}

// z1[b][o][p] = w0[o]*rg0[b][p] + w1[o]*rg1[b][p] + u[b][o]
__global__ void dec1_z_kernel(const float* __restrict__ rg, const float* __restrict__ dW1t,
                              const float* __restrict__ u, float* __restrict__ z1) {
  int bo = blockIdx.x;
  int b = bo / 1026;
  int o = bo - b * 1026;
  int t = threadIdx.x;
  float w0 = dW1t[o], w1 = dW1t[1026 + o], ub = u[bo];
  const float4* r0 = (const float4*)(rg + (size_t)b * 2 * NP);
  const float4* r1 = (const float4*)(rg + (size_t)b * 2 * NP + NP);
  float4* zr = (float4*)(z1 + (size_t)bo * NP);
  for (int i = t; i < NP / 4; i += 256) {
    float4 a = r0[i], c = r1[i], rr;
    rr.x = fmaf(w0, a.x, fmaf(w1, c.x, ub));
    rr.y = fmaf(w0, a.y, fmaf(w1, c.y, ub));
    rr.z = fmaf(w0, a.z, fmaf(w1, c.z, ub));
    rr.w = fmaf(w0, a.w, fmaf(w1, c.w, ub));
    zr[i] = rr;
  }
}

// per-channel stats over (b,p) of z [B][C][P] -> scale/shift (double accum)
__global__ void dstats_kernel(const float* __restrict__ z, int C, const float* __restrict__ g,
                              const float* __restrict__ be, float* __restrict__ scale,
                              float* __restrict__ shift) {
  int o = blockIdx.x, t = threadIdx.x;
  double s = 0.0, q = 0.0;
  for (int b = 0; b < 8; b++) {
    const float4* row = (const float4*)(z + ((size_t)b * C + o) * NP);
    for (int i = t; i < NP / 4; i += 256) {
      float4 v = row[i];
      s += (double)v.x + (double)v.y + (double)v.z + (double)v.w;
      q += (double)v.x * v.x + (double)v.y * v.y + (double)v.z * v.z + (double)v.w * v.w;
    }
  }
  __shared__ double rs[256], rq[256];
  rs[t] = s; rq[t] = q;
  __syncthreads();
  for (int st = 128; st; st >>= 1) {
    if (t < st) { rs[t] += rs[t + st]; rq[t] += rq[t + st]; }
    __syncthreads();
  }
  if (t == 0) {
    double inv = 1.0 / (8.0 * NP);
    double mean = rs[0] * inv;
    double var = rq[0] * inv - mean * mean;
    double r = 1.0 / sqrt(var + 1e-5);
    double sc = (double)g[o] * r;
    scale[o] = (float)sc;
    shift[o] = (float)((double)be[o] - mean * sc);
  }
}

// ---------------- decoder GEMM (64x128 tile, KSTEP=32, XCD-swizzled) ----------------
template <int NMT>
__global__ __launch_bounds__(256, 2) void dec_gemm64s_kernel(
    const float* __restrict__ zin, const float* __restrict__ Wt, int ldA,
    const float* __restrict__ bias, const float* __restrict__ scale,
    const float* __restrict__ shift, float* __restrict__ zout, int Ci, int Co) {
  __shared__ float sA[32][64];   // [c][m]
  __shared__ float sB[32][128];  // [c][p]
  int bid = blockIdx.x;
  int gl = bid & 7;
  int q = bid >> 3;
  int gh = q / NMT;
  int mt = q - gh * NMT;
  int g = gl + (gh << 3);  // in [0, 128)
  int pt = g & 15;
  int b = g >> 4;
  int m0 = mt * 64, p0 = pt * 128;
  int t = threadIdx.x;
  int lr = t >> 4, lcA = (t & 15) * 4, lcB = (t & 15) * 8;
  int tx = t & 15, ty = t >> 4;
  int numK = (Ci + 31) >> 5;
  float acc[4][8] = {};
  float rA[8], rB[16];

  auto gloadhalf = [&](int c, float* ra, float* rb) {
#pragma unroll
    for (int j = 0; j < 4; j++) ra[j] = 0.f;
#pragma unroll
    for (int j = 0; j < 8; j++) rb[j] = 0.f;
    if (c < Ci) {
      int mb = m0 + lcA;
      if (mb + 4 <= Co) {
        float4 a0 = *(const float4*)&Wt[(size_t)c * ldA + mb];
        ra[0] = a0.x; ra[1] = a0.y; ra[2] = a0.z; ra[3] = a0.w;
      } else {
#pragma unroll
        for (int j = 0; j < 4; j++)
          if (mb + j < Co) ra[j] = Wt[(size_t)c * ldA + mb + j];
      }
      float sc = scale[c], sh = shift[c];
      const float* src = &zin[((size_t)b * Ci + c) * NP + p0 + lcB];
      float4 z0 = *(const float4*)src;
      float4 z1 = *(const float4*)(src + 4);
      rb[0] = fmaxf(fmaf(sc, z0.x, sh), 0.f);
      rb[1] = fmaxf(fmaf(sc, z0.y, sh), 0.f);
      rb[2] = fmaxf(fmaf(sc, z0.z, sh), 0.f);
      rb[3] = fmaxf(fmaf(sc, z0.w, sh), 0.f);
      rb[4] = fmaxf(fmaf(sc, z1.x, sh), 0.f);
      rb[5] = fmaxf(fmaf(sc, z1.y, sh), 0.f);
      rb[6] = fmaxf(fmaf(sc, z1.z, sh), 0.f);
      rb[7] = fmaxf(fmaf(sc, z1.w, sh), 0.f);
    }
  };
  auto gload = [&](int kt) {
    gloadhalf(kt * 32 + lr, rA, rB);
    gloadhalf(kt * 32 + 16 + lr, rA + 4, rB + 8);
  };
  auto ldswrite = [&]() {
    float4 v0;
    v0.x = rA[0]; v0.y = rA[1]; v0.z = rA[2]; v0.w = rA[3];
    *(float4*)&sA[lr][lcA] = v0;
    v0.x = rA[4]; v0.y = rA[5]; v0.z = rA[6]; v0.w = rA[7];
    *(float4*)&sA[16 + lr][lcA] = v0;
    float4 w0, w1;
    w0.x = rB[0]; w0.y = rB[1]; w0.z = rB[2]; w0.w = rB[3];
    w1.x = rB[4]; w1.y = rB[5]; w1.z = rB[6]; w1.w = rB[7];
    *(float4*)&sB[lr][lcB] = w0;
    *(float4*)&sB[lr][lcB + 4] = w1;
    w0.x = rB[8]; w0.y = rB[9]; w0.z = rB[10]; w0.w = rB[11];
    w1.x = rB[12]; w1.y = rB[13]; w1.z = rB[14]; w1.w = rB[15];
    *(float4*)&sB[16 + lr][lcB] = w0;
    *(float4*)&sB[16 + lr][lcB + 4] = w1;
  };

  gload(0);
  for (int kt = 0; kt < numK; kt++) {
    __syncthreads();
    ldswrite();
    __syncthreads();
    if (kt + 1 < numK) gload(kt + 1);
#pragma unroll
    for (int c = 0; c < 32; c++) {
      float4 a0 = *(const float4*)&sA[c][ty * 4];
      float4 b0 = *(const float4*)&sB[c][tx * 4];
      float4 b1 = *(const float4*)&sB[c][64 + tx * 4];
      float av[4] = {a0.x, a0.y, a0.z, a0.w};
      float bv[8] = {b0.x, b0.y, b0.z, b0.w, b1.x, b1.y, b1.z, b1.w};
#pragma unroll
      for (int i = 0; i < 4; i++)
#pragma unroll
        for (int j = 0; j < 8; j++) acc[i][j] = fmaf(av[i], bv[j], acc[i][j]);
    }
  }
#pragma unroll
  for (int i = 0; i < 4; i++) {
    int m = m0 + ty * 4 + i;
    if (m < Co) {
      float bv = bias[m];
      float* dst = &zout[((size_t)b * Co + m) * NP + p0];
      float4 q0, q1;
      q0.x = acc[i][0] + bv; q0.y = acc[i][1] + bv;
      q0.z = acc[i][2] + bv; q0.w = acc[i][3] + bv;
      q1.x = acc[i][4] + bv; q1.y = acc[i][5] + bv;
      q1.z = acc[i][6] + bv; q1.w = acc[i][7] + bv;
      *(float4*)&dst[tx * 4] = q0;
      *(float4*)&dst[64 + tx * 4] = q1;
    }
  }
}

// ---------------- final layer (c-split, 256 blocks) ----------------
__global__ void dec_final_kernel(const float* __restrict__ z3, const float* __restrict__ dW4,
                                 const float* __restrict__ db4, const float* __restrict__ scale,
                                 const float* __restrict__ shift, float* __restrict__ out) {
  __shared__ float w4[3 * 256];
  __shared__ float sc[256], sh[256];
  __shared__ float red[4][64][3];
  int b = blockIdx.x, pc = blockIdx.y, t = threadIdx.x;
  for (int e = t; e < 768; e += 256) w4[e] = dW4[e];
  sc[t] = scale[t];
  sh[t] = shift[t];
  __syncthreads();
  int tp = t & 63, tc = t >> 6;
  int p = pc * 64 + tp;
  float a0 = 0.f, a1 = 0.f, a2 = 0.f;
  for (int c = tc * 64; c < tc * 64 + 64; c++) {
    float hv = fmaxf(fmaf(sc[c], z3[((size_t)(b * 256 + c)) * NP + p], sh[c]), 0.f);
    a0 = fmaf(w4[c], hv, a0);
    a1 = fmaf(w4[256 + c], hv, a1);
    a2 = fmaf(w4[512 + c], hv, a2);
  }
  red[tc][tp][0] = a0;
  red[tc][tp][1] = a1;
  red[tc][tp][2] = a2;
  __syncthreads();
  if (tc == 0) {
    a0 = red[0][tp][0] + red[1][tp][0] + red[2][tp][0] + red[3][tp][0];
    a1 = red[0][tp][1] + red[1][tp][1] + red[2][tp][1] + red[3][tp][1];
    a2 = red[0][tp][2] + red[1][tp][2] + red[2][tp][2] + red[3][tp][2];
    out[((size_t)b * 3 + 0) * NP + p] = tanhf(a0 + db4[0]);
    out[((size_t)b * 3 + 1) * NP + p] = tanhf(a1 + db4[1]);
    out[((size_t)b * 3 + 2) * NP + p] = tanhf(a2 + db4[2]);
  }
}

// ---------------- host ----------------

extern "C" void kernel_launch(void* const* d_in, const int* in_sizes, int n_in, void* d_out,
                              int out_size, void* d_ws, size_t ws_size, hipStream_t stream) {
  const float* x = (const float*)d_in[0];
  const float* rg = (const float*)d_in[1];
  const float* W1 = (const float*)d_in[2];
  const float* b1 = (const float*)d_in[3];
  const float* g1 = (const float*)d_in[4];
  const float* be1 = (const float*)d_in[5];
  const float* W2 = (const float*)d_in[6];
  const float* b2 = (const float*)d_in[7];
  const float* g2 = (const float*)d_in[8];
  const float* be2 = (const float*)d_in[9];
  const float* W3 = (const float*)d_in[10];
  const float* b3 = (const float*)d_in[11];
  const float* g3 = (const float*)d_in[12];
  const float* be3 = (const float*)d_in[13];
  const float* W4 = (const float*)d_in[14];
  const float* b4 = (const float*)d_in[15];
  const float* g4 = (const float*)d_in[16];
  const float* be4 = (const float*)d_in[17];
  const float* W5 = (const float*)d_in[18];
  const float* b5 = (const float*)d_in[19];
  const float* g5 = (const float*)d_in[20];
  const float* be5 = (const float*)d_in[21];
  const float* lW = (const float*)d_in[22];
  const float* lb = (const float*)d_in[23];
  const float* lg = (const float*)d_in[24];
  const float* lbe = (const float*)d_in[25];
  const float* dW1 = (const float*)d_in[26];
  const float* db1 = (const float*)d_in[27];
  const float* dg1 = (const float*)d_in[28];
  const float* dbe1 = (const float*)d_in[29];
  const float* dW2 = (const float*)d_in[30];
  const float* db2 = (const float*)d_in[31];
  const float* dg2 = (const float*)d_in[32];
  const float* dbe2 = (const float*)d_in[33];
  const float* dW3 = (const float*)d_in[34];
  const float* db3 = (const float*)d_in[35];
  const float* dg3 = (const float*)d_in[36];
  const float* dbe3 = (const float*)d_in[37];
  const float* dW4 = (const float*)d_in[38];
  const float* db4 = (const float*)d_in[39];
  float* out = (float*)d_out;

  float* ws = (float*)d_ws;
  size_t off = 0;
  auto alloc = [&](size_t n) {
    size_t r = off;
    off += (n + 255) & ~(size_t)255;
    return r;
  };
  size_t f_pts = alloc((size_t)NB * NN * 3);
  // UnionA: cat + idx + zmax + zmin + psumf + psqf ; overlaid later by z2
  size_t f_uA = alloc(13959168);
  size_t f_cat = f_uA;
  size_t f_idx = f_cat + 5242880;
  size_t f_zmax = f_idx + 327680;
  size_t f_zmin = f_zmax + 2097152;
  size_t f_psum = f_zmin + 2097152;
  size_t f_psq = f_psum + 2097152;
  size_t f_z2 = f_uA;
  // UnionB: P (<=4.2M) -> z5 -> z1
  size_t f_uB = alloc(16809984);
  size_t f_z5 = f_uB, f_z1 = f_uB;
  float* P = ws + f_uB;
  // UnionC: W5 stats partials (doubles+floats) -> z3
  size_t f_uC = alloc(4194304);
  double* ps5_d = (double*)(ws + f_uC);  // 262,144 doubles
  double* pq5_d = ps5_d + 262144;        // 262,144 doubles
  size_t f_pM5 = f_uC + 2097152;
  size_t f_pm5 = f_pM5 + 262144;
  size_t f_z3 = f_uC;
  size_t f_weff = alloc(256 * 64);
  size_t f_W5t = alloc(320 * 1024);
  size_t f_lWt = alloc(1024 * 1024);
  size_t f_dW1t = alloc((size_t)1026 * 1026);
  size_t f_dW2t = alloc((size_t)1026 * 516);  // padded ld=516 for alignment
  size_t f_dW3t = alloc(513 * 256);
  size_t f_scale = alloc(2048);
  size_t f_shift = alloc(2048);
  size_t f_glob = alloc(8 * 1024);
  size_t f_latp = alloc(8 * 1024);
  size_t f_lat = alloc(8 * 1024);
  size_t f_u = alloc(8 * 1026);
  (void)ws_size;
  (void)in_sizes;
  (void)n_in;
  (void)out_size;

  float* cat = ws + f_cat;
  int* idxp = (int*)(ws + f_idx);
  float* zmax = ws + f_zmax;
  float* zmin = ws + f_zmin;
  float* psumf = ws + f_psum;
  float* psqf = ws + f_psq;
  float* weff = ws + f_weff;
  float* scale = ws + f_scale;
  float* shift = ws + f_shift;
  const double invn_e = 1.0 / (double)(NB * NN * NK);

  // prep
  transpose_x_kernel<<<192, 256, 0, stream>>>(x, ws + f_pts);
  transpose_mat_ld<<<dim3(10, 32), 256, 0, stream>>>(W5, ws + f_W5t, 1024, 320, 1024);
  transpose_mat_ld<<<dim3(32, 32), 256, 0, stream>>>(lW, ws + f_lWt, 1024, 1024, 1024);
  transpose_mat_ld<<<dim3(33, 33), 256, 0, stream>>>(dW1, ws + f_dW1t, 1026, 1026, 1026);
  transpose_mat_ld<<<dim3(33, 17), 256, 0, stream>>>(dW2, ws + f_dW2t, 513, 1026, 516);
  transpose_mat_ld<<<dim3(17, 8), 256, 0, stream>>>(dW3, ws + f_dW3t, 256, 513, 256);

  // ---- edge layer 1 (pts, D=3 -> 64 @ cat[0:64)) ----
  knn3_fused_kernel<<<NB * NN / 4, 256, 0, stream>>>(ws + f_pts, idxp);
  weff_kernel<<<2, 256, 0, stream>>>(W1, 64, 3, weff);
  pgemm_kernel<128, 3><<<2048, 256, 0, stream>>>(ws + f_pts, 3, 0, weff, b1, P);
  combine_kernel<64><<<4096, 256, 0, stream>>>(P, idxp, zmax, zmin, psumf, psqf);
  edge_reduce_kernel<<<64, 256, 0, stream>>>(psumf, psqf, g1, be1, scale, shift, invn_e);
  edge_affine_kernel<<<NB * NN * 64 / 256, 256, 0, stream>>>(zmax, zmin, scale, shift, cat, 64, 0);
  // ---- edge layer 2 (cat[0:64) -> cat[64:128)) ----
  knn64_fused4_kernel<<<dim3(128, 8), 256, 0, stream>>>(cat, 320, 0, idxp);
  weff_kernel<<<32, 256, 0, stream>>>(W2, 64, 64, weff);
  pgemm_kernel<128, 64><<<2048, 256, 0, stream>>>(cat, 320, 0, weff, b2, P);
  combine_kernel<64><<<4096, 256, 0, stream>>>(P, idxp, zmax, zmin, psumf, psqf);
  edge_reduce_kernel<<<64, 256, 0, stream>>>(psumf, psqf, g2, be2, scale, shift, invn_e);
  edge_affine_kernel<<<NB * NN * 64 / 256, 256, 0, stream>>>(zmax, zmin, scale, shift, cat, 64, 64);
  // ---- edge layer 3 (cat[64:128) -> cat[128:192)) ----
  knn64_fused4_kernel<<<dim3(128, 8), 256, 0, stream>>>(cat, 320, 64, idxp);
  weff_kernel<<<32, 256, 0, stream>>>(W3, 64, 64, weff);
  pgemm_kernel<128, 64><<<2048, 256, 0, stream>>>(cat, 320, 64, weff, b3, P);
  combine_kernel<64><<<4096, 256, 0, stream>>>(P, idxp, zmax, zmin, psumf, psqf);
  edge_reduce_kernel<<<64, 256, 0, stream>>>(psumf, psqf, g3, be3, scale, shift, invn_e);
  edge_affine_kernel<<<NB * NN * 64 / 256, 256, 0, stream>>>(zmax, zmin, scale, shift, cat, 64, 128);
  // ---- edge layer 4 (cat[128:192) -> cat[192:320)) ----
  knn64_fused4_kernel<<<dim3(128, 8), 256, 0, stream>>>(cat, 320, 128, idxp);
  weff_kernel<<<64, 256, 0, stream>>>(W4, 128, 64, weff);
  pgemm_kernel<256, 64><<<2048, 256, 0, stream>>>(cat, 320, 128, weff, b4, P);
  combine_kernel<128><<<8192, 256, 0, stream>>>(P, idxp, zmax, zmin, psumf, psqf);
  edge_reduce_kernel<<<128, 256, 0, stream>>>(psumf, psqf, g4, be4, scale, shift, invn_e);
  edge_affine_kernel<<<NB * NN * 128 / 256, 256, 0, stream>>>(zmax, zmin, scale, shift, cat, 128, 192);

  // ---- W5 GEMM + global max ----
  gemm5_64_kernel<<<dim3(256, 8), 256, 0, stream>>>(cat, ws + f_W5t, b5, ws + f_z5);
  stats5_kernel<<<256, 256, 0, stream>>>(ws + f_z5, ps5_d, pq5_d, ws + f_pM5, ws + f_pm5);
  reduce5_glob_kernel<<<4, 256, 0, stream>>>(ps5_d, pq5_d, ws + f_pM5, ws + f_pm5, g5, be5,
                                             ws + f_glob);
  // ---- latent ----
  fc_kernel<<<dim3(8, 32), 256, 0, stream>>>(ws + f_glob, ws + f_lWt, 1024, 0, lb, ws + f_latp,
                                             1024, 1024);
  lat_bn_kernel<<<4, 256, 0, stream>>>(ws + f_latp, lg, lbe, ws + f_lat);
  // ---- decoder ----
  fc_kernel<<<dim3(8, 33), 256, 0, stream>>>(ws + f_lat, ws + f_dW1t, 1026, 2, db1, ws + f_u, 1024,
                                             1026);
  dec1_z_kernel<<<8 * 1026, 256, 0, stream>>>(rg, ws + f_dW1t, ws + f_u, ws + f_z1);
  dstats_kernel<<<1026, 256, 0, stream>>>(ws + f_z1, 1026, dg1, dbe1, scale, shift);
  dec_gemm64s_kernel<9><<<9 * 128, 256, 0, stream>>>(ws + f_z1, ws + f_dW2t, 516, db2, scale,
                                                     shift, ws + f_z2, 1026, 513);
  dstats_kernel<<<513, 256, 0, stream>>>(ws + f_z2, 513, dg2, dbe2, scale, shift);
  dec_gemm64s_kernel<4><<<4 * 128, 256, 0, stream>>>(ws + f_z2, ws + f_dW3t, 256, db3, scale,
                                                     shift, ws + f_z3, 513, 256);
  dstats_kernel<<<256, 256, 0, stream>>>(ws + f_z3, 256, dg3, dbe3, scale, shift);
  dec_final_kernel<<<dim3(8, 32), 256, 0, stream>>>(ws + f_z3, dW4, db4, scale, shift, out);
}

// Round 18
// 1831.415 us; speedup vs baseline: 1.1026x; 1.1026x over previous
//
#include <hip/hip_runtime.h>
#include <math.h>

constexpr int NB = 8;      // batch
constexpr int NN = 2048;   // points
constexpr int NK = 20;     // knn
constexpr int NP = 2048;   // decoder points

// ---------------- utils ----------------

__global__ void transpose_x_kernel(const float* __restrict__ x, float* __restrict__ pts) {
  int gid = blockIdx.x * 256 + threadIdx.x;  // over B*N*3 outputs [b][n][c]
  if (gid >= NB * NN * 3) return;
  int c = gid % 3;
  int n = (gid / 3) % NN;
  int b = gid / (3 * NN);
  pts[gid] = x[(b * 3 + c) * NN + n];
}

// dst[c*ldd + r] = src[r*C + c]
__global__ void transpose_mat_ld(const float* __restrict__ src, float* __restrict__ dst, int R,
                                 int C, int ldd) {
  __shared__ float tile[32][33];
  int c0 = blockIdx.x * 32, r0 = blockIdx.y * 32;
  int tx = threadIdx.x & 31, ty = threadIdx.x >> 5;  // 32 x 8
  for (int i = ty; i < 32; i += 8) {
    int r = r0 + i, c = c0 + tx;
    tile[i][tx] = (r < R && c < C) ? src[(size_t)r * C + c] : 0.f;
  }
  __syncthreads();
  for (int i = ty; i < 32; i += 8) {
    int c = c0 + i, r = r0 + tx;
    if (r < R && c < C) dst[(size_t)c * ldd + r] = tile[tx][i];
  }
}

// ---------------- KNN layer 1 (D=3): fused dist + top-20 ----------------
__global__ void knn3_fused_kernel(const float* __restrict__ pts, int* __restrict__ idx) {
  __shared__ float sm[3][NN];  // [dim][col]
  int t = threadIdx.x;
  int l = t & 63, w = t >> 6;
  int gb = blockIdx.x;    // over B*NN/4
  int b = gb >> 9;        // 512 blocks per batch
  int n0 = (gb & 511) * 4;
  const float* base = pts + (size_t)b * NN * 3;
  for (int e = t; e < NN * 3; e += 256) {
    int col = e / 3, d = e - col * 3;
    sm[d][col] = base[e];
  }
  __syncthreads();
  int n = n0 + w;
  float c0 = sm[0][n], c1 = sm[1][n], c2 = sm[2][n];
  float v[32];
#pragma unroll
  for (int j = 0; j < 32; j++) {
    int col = j * 64 + l;
    float d0 = c0 - sm[0][col];
    float d1 = c1 - sm[1][col];
    float d2 = c2 - sm[2][col];
    float acc = 0.f;
    acc = fmaf(d0, d0, acc);
    acc = fmaf(d1, d1, acc);
    acc = fmaf(d2, d2, acc);
    v[j] = -acc;
  }
  int mykm = 0;
  for (int k = 0; k < NK; k++) {
    float bv = v[0];
    int bj = 0;
#pragma unroll
    for (int j = 1; j < 32; j++) {
      if (v[j] > bv) { bv = v[j]; bj = j; }
    }
    int gm = bj * 64 + l;
#pragma unroll
    for (int off = 32; off; off >>= 1) {
      float ov = __shfl_xor(bv, off, 64);
      int om = __shfl_xor(gm, off, 64);
      if (ov > bv || (ov == bv && om < gm)) { bv = ov; gm = om; }
    }
    if (l == k) mykm = gm;
    int jb = gm >> 6, lb = gm & 63;
#pragma unroll
    for (int j = 0; j < 32; j++)
      if (j == jb && l == lb) v[j] = -3e38f;
  }
  if (l < NK) idx[((size_t)(b * NN + n)) * NK + l] = mykm;
}

// ---------------- KNN D=64: fused dist + top-20, 2 centers/wave, 1024 thr ----------------
// 1024-thread block (16 waves) owns 32 center rows; wave w owns centers
// n0+2w, n0+2w+1. Features stream through LDS in 16 transposed 128-col tiles
// (conflict-free staging: colg = t&127 spans lanes). Per d: two conflict-free
// scalar reads (cols l, 64+l) amortized over 2 centers (4 fma). Distances
// bit-identical to the two-phase path (same fmaf chain, d ascending).
// Slot j of lane l holds col (j>>1)*128 + (j&1)*64 + l (ascending in j).
__global__ __launch_bounds__(1024, 4) void knn64_fused2_kernel(const float* __restrict__ h,
                                                               int ld, int coff,
                                                               int* __restrict__ idx) {
  __shared__ float sft[64][128];  // feature tile [dim][col_local]
  __shared__ float sctr[32][64];  // 32 center rows
  int t = threadIdx.x;
  int l = t & 63, w = t >> 6;  // wave 0..15
  int n0 = blockIdx.x * 32;
  int b = blockIdx.y;
  const float* rows = h + (size_t)b * NN * ld + coff;
  for (int e = t; e < 32 * 64; e += 1024) {
    int r = e >> 6, d = e & 63;
    sctr[r][d] = rows[(size_t)(n0 + r) * ld + d];
  }
  int colg = t & 127;        // 0..127 (spans lanes -> conflict-free writes)
  int dh = (t >> 7) * 8;     // dim offset, 8 groups x 8 dims
  float v[2][32];
#pragma unroll
  for (int ct = 0; ct < 16; ct++) {
    __syncthreads();
    {
      const float* src = &rows[(size_t)(ct * 128 + colg) * ld + dh];
      float4 f0 = *(const float4*)src;
      float4 f1 = *(const float4*)(src + 4);
      sft[dh + 0][colg] = f0.x;
      sft[dh + 1][colg] = f0.y;
      sft[dh + 2][colg] = f0.z;
      sft[dh + 3][colg] = f0.w;
      sft[dh + 4][colg] = f1.x;
      sft[dh + 5][colg] = f1.y;
      sft[dh + 6][colg] = f1.z;
      sft[dh + 7][colg] = f1.w;
    }
    __syncthreads();
    float a00 = 0.f, a01 = 0.f, a10 = 0.f, a11 = 0.f;
#pragma unroll 8
    for (int d = 0; d < 64; d++) {
      float f0 = sft[d][l];       // lane-stride 1 -> conflict-free
      float f1 = sft[d][64 + l];  // lane-stride 1 -> conflict-free
      float c0v = sctr[2 * w + 0][d];  // wave-uniform broadcast
      float c1v = sctr[2 * w + 1][d];
      float e;
      e = c0v - f0; a00 = fmaf(e, e, a00);
      e = c0v - f1; a01 = fmaf(e, e, a01);
      e = c1v - f0; a10 = fmaf(e, e, a10);
      e = c1v - f1; a11 = fmaf(e, e, a11);
    }
    v[0][2 * ct] = -a00; v[0][2 * ct + 1] = -a01;
    v[1][2 * ct] = -a10; v[1][2 * ct + 1] = -a11;
  }
#pragma unroll
  for (int ci = 0; ci < 2; ci++) {
    int mykm = 0;
    for (int k = 0; k < NK; k++) {
      float bv = v[ci][0];
      int bj = 0;
#pragma unroll
      for (int j = 1; j < 32; j++) {
        if (v[ci][j] > bv) { bv = v[ci][j]; bj = j; }  // strict >: smallest col in-lane
      }
      int gm = ((bj >> 1) << 7) + ((bj & 1) << 6) + l;
#pragma unroll
      for (int off = 32; off; off >>= 1) {
        float ov = __shfl_xor(bv, off, 64);
        int om = __shfl_xor(gm, off, 64);
        if (ov > bv || (ov == bv && om < gm)) { bv = ov; gm = om; }
      }
      if (l == k) mykm = gm;
      int jb = ((gm >> 7) << 1) + ((gm >> 6) & 1);
      int lb = gm & 63;
#pragma unroll
      for (int j = 0; j < 32; j++)
        if (j == jb && l == lb) v[ci][j] = -3e38f;
    }
    if (l < NK) idx[((size_t)(b * NN + n0 + 2 * w + ci)) * NK + l] = mykm;
  }
}

// ---------------- Edge conv factorized: Weff, pgemm, combine ----------------
__global__ void weff_kernel(const float* __restrict__ W, int O, int D, float* __restrict__ Weff) {
  int i = blockIdx.x * 256 + threadIdx.x;  // over 2O*D
  if (i >= 2 * O * D) return;
  int o = i / D, d = i - o * D;
  float v;
  if (o < O) v = W[(size_t)o * 2 * D + d] - W[(size_t)o * 2 * D + D + d];
  else v = W[(size_t)(o - O) * 2 * D + D + d];
  Weff[i] = v;
}

// P[n][0..O) = bias + Weff[0..O) . h[n]; P[n][O..2O) = Weff[O..) . h[n]
template <int M2, int D>
__global__ __launch_bounds__(256, 4) void pgemm_kernel(const float* __restrict__ h, int ld,
                                                       int coff, const float* __restrict__ Weff,
                                                       const float* __restrict__ bias,
                                                       float* __restrict__ P) {
  constexpr int O = M2 / 2;
  constexpr int GRP = 256 / M2;  // 2 or 1
  constexpr int NR = 8 / GRP;    // 4 or 8
  __shared__ float sh[8][D == 3 ? 4 : 68];
  int t = threadIdx.x;
  int n0 = blockIdx.x * 8;
  const float* base = h + coff;
  if constexpr (D == 64) {
    if (t < 128) {
      int r = t >> 4, q = (t & 15) * 4;
      *(float4*)&sh[r][q] = *(const float4*)&base[(size_t)(n0 + r) * ld + q];
    }
  } else {
    if (t < 24) {
      int r = t / 3, c = t - r * 3;
      sh[r][c] = base[(size_t)(n0 + r) * ld + c];
    }
  }
  __syncthreads();
  int o = t % M2;
  int gi = t / M2;
  float acc[NR];
  float bz = (o < O) ? bias[o] : 0.f;
#pragma unroll
  for (int j = 0; j < NR; j++) acc[j] = bz;
  const float* wr = Weff + (size_t)o * D;
  if constexpr (D == 64) {
#pragma unroll
    for (int d4 = 0; d4 < 16; d4++) {
      float4 w4 = *(const float4*)&wr[d4 * 4];
#pragma unroll
      for (int j = 0; j < NR; j++) {
        float4 e4 = *(const float4*)&sh[gi * NR + j][d4 * 4];
        acc[j] = fmaf(w4.x, e4.x, acc[j]);
        acc[j] = fmaf(w4.y, e4.y, acc[j]);
        acc[j] = fmaf(w4.z, e4.z, acc[j]);
        acc[j] = fmaf(w4.w, e4.w, acc[j]);
      }
    }
  } else {
    float w0 = wr[0], w1 = wr[1], w2 = wr[2];
#pragma unroll
    for (int j = 0; j < NR; j++) {
      int r = gi * NR + j;
      acc[j] = fmaf(w0, sh[r][0], fmaf(w1, sh[r][1], fmaf(w2, sh[r][2], acc[j])));
    }
  }
#pragma unroll
  for (int j = 0; j < NR; j++)
    P[(size_t)(n0 + gi * NR + j) * M2 + o] = acc[j];
}

// z[n,k,o] = relu(P1[n][o] + P2[idx[n,k]][o]); track max/min over k + f32 sum/sumsq
template <int O>
__global__ __launch_bounds__(256, 8) void combine_kernel(const float* __restrict__ P,
                                                         const int* __restrict__ idx,
                                                         float* __restrict__ zmax,
                                                         float* __restrict__ zmin,
                                                         float* __restrict__ psum,
                                                         float* __restrict__ psq) {
  constexpr int CPB = 256 / O;
  constexpr int M2 = 2 * O;
  __shared__ int sidx[CPB * NK];
  int t = threadIdx.x;
  int bn0 = blockIdx.x * CPB;
  if (t < CPB * NK) sidx[t] = idx[(size_t)bn0 * NK + t];
  __syncthreads();
  int g = t / O, o = t % O;
  int bn = bn0 + g;
  int b = bn >> 11;
  float p1 = P[(size_t)bn * M2 + o];
  const float* P2 = P + (size_t)b * NN * M2 + O + o;
  float s = 0.f, sq = 0.f, mx = -3e38f, mn = 3e38f;
#pragma unroll
  for (int k = 0; k < NK; k++) {
    int nb = sidx[g * NK + k];
    float z = fmaxf(p1 + P2[(size_t)nb * M2], 0.f);
    s += z;
    sq = fmaf(z, z, sq);
    mx = fmaxf(mx, z);
    mn = fminf(mn, z);
  }
  zmax[(size_t)bn * O + o] = mx;
  zmin[(size_t)bn * O + o] = mn;
  psum[(size_t)o * (NB * NN) + bn] = s;
  psq[(size_t)o * (NB * NN) + bn] = sq;
}

__global__ void edge_reduce_kernel(const float* __restrict__ psum, const float* __restrict__ psq,
                                   const float* __restrict__ g, const float* __restrict__ be,
                                   float* __restrict__ scale, float* __restrict__ shift,
                                   double inv_n) {
  int o = blockIdx.x, t = threadIdx.x;
  double s = 0.0, q = 0.0;
  const float* ps = psum + (size_t)o * (NB * NN);
  const float* pq = psq + (size_t)o * (NB * NN);
  for (int i = t; i < NB * NN; i += 256) { s += (double)ps[i]; q += (double)pq[i]; }
  __shared__ double rs[256], rq[256];
  rs[t] = s; rq[t] = q;
  __syncthreads();
  for (int st = 128; st; st >>= 1) {
    if (t < st) { rs[t] += rs[t + st]; rq[t] += rq[t + st]; }
    __syncthreads();
  }
  if (t == 0) {
    double mean = rs[0] * inv_n;
    double var = rq[0] * inv_n - mean * mean;
    double r = 1.0 / sqrt(var + 1e-5);
    double sc = (double)g[o] * r;
    scale[o] = (float)sc;
    shift[o] = (float)((double)be[o] - mean * sc);
  }
}

__global__ void edge_affine_kernel(const float* __restrict__ zmax, const float* __restrict__ zmin,
                                   const float* __restrict__ scale, const float* __restrict__ shift,
                                   float* __restrict__ cat, int O, int coff_out) {
  int gid = blockIdx.x * 256 + threadIdx.x;  // over B*N*O
  int o = gid % O;
  int bn = gid / O;
  float sc = scale[o];
  float v = (sc >= 0.f) ? zmax[gid] : zmin[gid];
  cat[(size_t)bn * 320 + coff_out + o] = fmaf(sc, v, shift[o]);
}

// ---------------- W5 GEMM (64x128 tile, 4x8/thread, KSTEP=32) ----------------
__global__ __launch_bounds__(256, 2) void gemm5_64_kernel(const float* __restrict__ cat,
                                                          const float* __restrict__ W5t,
                                                          const float* __restrict__ b5,
                                                          float* __restrict__ z5) {
  __shared__ float sA[32][64];   // [c][row]
  __shared__ float sB[32][128];  // [c][m]
  int t = threadIdx.x;
  int r0 = blockIdx.x * 64, m0 = blockIdx.y * 128;
  int arow = t & 63, ach = (t >> 6) * 8;   // A: row, 8 c's
  int blr = t >> 4, blc = (t & 15) * 8;    // B: c in [0,16), 8 m's
  int tx = t & 15, ty = t >> 4;
  float acc[4][8] = {};
  float rA[8], rB[16];

  auto gload = [&](int c0) {
    const float* pa = &cat[(size_t)(r0 + arow) * 320 + c0 + ach];
    float4 a0 = *(const float4*)pa;
    float4 a1 = *(const float4*)(pa + 4);
    rA[0] = a0.x; rA[1] = a0.y; rA[2] = a0.z; rA[3] = a0.w;
    rA[4] = a1.x; rA[5] = a1.y; rA[6] = a1.z; rA[7] = a1.w;
    const float* pb = &W5t[(size_t)(c0 + blr) * 1024 + m0 + blc];
    float4 b0 = *(const float4*)pb;
    float4 b1 = *(const float4*)(pb + 4);
    rB[0] = b0.x; rB[1] = b0.y; rB[2] = b0.z; rB[3] = b0.w;
    rB[4] = b1.x; rB[5] = b1.y; rB[6] = b1.z; rB[7] = b1.w;
    const float* pb2 = &W5t[(size_t)(c0 + 16 + blr) * 1024 + m0 + blc];
    float4 c4 = *(const float4*)pb2;
    float4 c5 = *(const float4*)(pb2 + 4);
    rB[8] = c4.x; rB[9] = c4.y; rB[10] = c4.z; rB[11] = c4.w;
    rB[12] = c5.x; rB[13] = c5.y; rB[14] = c5.z; rB[15] = c5.w;
  };
  auto ldswrite = [&]() {
#pragma unroll
    for (int j = 0; j < 8; j++) sA[ach + j][arow] = rA[j];
    float4 w0, w1;
    w0.x = rB[0]; w0.y = rB[1]; w0.z = rB[2]; w0.w = rB[3];
    w1.x = rB[4]; w1.y = rB[5]; w1.z = rB[6]; w1.w = rB[7];
    *(float4*)&sB[blr][blc] = w0;
    *(float4*)&sB[blr][blc + 4] = w1;
    w0.x = rB[8]; w0.y = rB[9]; w0.z = rB[10]; w0.w = rB[11];
    w1.x = rB[12]; w1.y = rB[13]; w1.z = rB[14]; w1.w = rB[15];
    *(float4*)&sB[16 + blr][blc] = w0;
    *(float4*)&sB[16 + blr][blc + 4] = w1;
  };

  gload(0);
  for (int kt = 0; kt < 10; kt++) {
    __syncthreads();
    ldswrite();
    __syncthreads();
    if (kt + 1 < 10) gload((kt + 1) * 32);
#pragma unroll
    for (int c = 0; c < 32; c++) {
      float4 a0 = *(const float4*)&sA[c][ty * 4];
      float4 b0 = *(const float4*)&sB[c][tx * 4];
      float4 b1 = *(const float4*)&sB[c][64 + tx * 4];
      float av[4] = {a0.x, a0.y, a0.z, a0.w};
      float bv[8] = {b0.x, b0.y, b0.z, b0.w, b1.x, b1.y, b1.z, b1.w};
#pragma unroll
      for (int i = 0; i < 4; i++)
#pragma unroll
        for (int j = 0; j < 8; j++) acc[i][j] = fmaf(av[i], bv[j], acc[i][j]);
    }
  }
  float bj[8];
#pragma unroll
  for (int j = 0; j < 8; j++)
    bj[j] = b5[m0 + (j < 4 ? tx * 4 + j : 64 + tx * 4 + (j - 4))];
#pragma unroll
  for (int i = 0; i < 4; i++) {
    int r = r0 + ty * 4 + i;
    float* dst = &z5[(size_t)r * 1024 + m0];
    float4 q0, q1;
    q0.x = fmaxf(acc[i][0] + bj[0], 0.f);
    q0.y = fmaxf(acc[i][1] + bj[1], 0.f);
    q0.z = fmaxf(acc[i][2] + bj[2], 0.f);
    q0.w = fmaxf(acc[i][3] + bj[3], 0.f);
    q1.x = fmaxf(acc[i][4] + bj[4], 0.f);
    q1.y = fmaxf(acc[i][5] + bj[5], 0.f);
    q1.z = fmaxf(acc[i][6] + bj[6], 0.f);
    q1.w = fmaxf(acc[i][7] + bj[7], 0.f);
    *(float4*)&dst[tx * 4] = q0;
    *(float4*)&dst[64 + tx * 4] = q1;
  }
}

__global__ void stats5_kernel(const float* __restrict__ z5, double* __restrict__ psum5,
                              double* __restrict__ psq5, float* __restrict__ pmax5,
                              float* __restrict__ pmin5) {
  int j = blockIdx.x, t = threadIdx.x;
  int row0 = j * 64;
  double s0 = 0, s1 = 0, s2 = 0, s3 = 0, q0 = 0, q1 = 0, q2 = 0, q3 = 0;
  float4 mx = {-3e38f, -3e38f, -3e38f, -3e38f}, mn = {3e38f, 3e38f, 3e38f, 3e38f};
  for (int r = 0; r < 64; r++) {
    float4 v = *(const float4*)&z5[(size_t)(row0 + r) * 1024 + t * 4];
    s0 += v.x; s1 += v.y; s2 += v.z; s3 += v.w;
    q0 += (double)v.x * v.x; q1 += (double)v.y * v.y;
    q2 += (double)v.z * v.z; q3 += (double)v.w * v.w;
    mx.x = fmaxf(mx.x, v.x); mx.y = fmaxf(mx.y, v.y); mx.z = fmaxf(mx.z, v.z); mx.w = fmaxf(mx.w, v.w);
    mn.x = fminf(mn.x, v.x); mn.y = fminf(mn.y, v.y); mn.z = fminf(mn.z, v.z); mn.w = fminf(mn.w, v.w);
  }
  size_t base = (size_t)j * 1024 + t * 4;
  psum5[base + 0] = s0; psum5[base + 1] = s1; psum5[base + 2] = s2; psum5[base + 3] = s3;
  psq5[base + 0] = q0; psq5[base + 1] = q1; psq5[base + 2] = q2; psq5[base + 3] = q3;
  *(float4*)&pmax5[base] = mx;
  *(float4*)&pmin5[base] = mn;
}

__global__ void reduce5_glob_kernel(const double* __restrict__ psum5, const double* __restrict__ psq5,
                                    const float* __restrict__ pmax5, const float* __restrict__ pmin5,
                                    const float* __restrict__ g5, const float* __restrict__ be5,
                                    float* __restrict__ glob) {
  int o = blockIdx.x * 256 + threadIdx.x;
  double s = 0.0, q = 0.0;
  for (int j = 0; j < 256; j++) {
    s += psum5[(size_t)j * 1024 + o];
    q += psq5[(size_t)j * 1024 + o];
  }
  double mean = s * (1.0 / 16384.0);
  double var = q * (1.0 / 16384.0) - mean * mean;
  double r = 1.0 / sqrt(var + 1e-5);
  double scd = (double)g5[o] * r;
  float sc = (float)scd;
  float sh = (float)((double)be5[o] - mean * scd);
  for (int b = 0; b < 8; b++) {
    float m;
    if (sc >= 0.f) {
      m = -3e38f;
      for (int jj = 0; jj < 32; jj++) m = fmaxf(m, pmax5[(size_t)(b * 32 + jj) * 1024 + o]);
    } else {
      m = 3e38f;
      for (int jj = 0; jj < 32; jj++) m = fminf(m, pmin5[(size_t)(b * 32 + jj) * 1024 + o]);
    }
    glob[b * 1024 + o] = fmaf(sc, m, sh);
  }
}

// ---------------- fully-connected helper (o-tiled, 8-way c-split) ----------------
__global__ void fc_kernel(const float* __restrict__ in, const float* __restrict__ Wt, int ld,
                          int coff, const float* __restrict__ bias, float* __restrict__ out,
                          int Ci, int Co) {
  __shared__ float sin_[1024];
  __shared__ float red[8][32];
  int b = blockIdx.x, t = threadIdx.x;
  for (int e = t; e < Ci; e += 256) sin_[e] = in[(size_t)b * Ci + e];
  __syncthreads();
  int o = blockIdx.y * 32 + (t & 31);
  int cg = t >> 5;
  int cn = Ci / 8;
  float p = 0.f;
  if (o < Co) {
    for (int c = cg * cn; c < (cg + 1) * cn; c++)
      p = fmaf(Wt[(size_t)(c + coff) * ld + o], sin_[c], p);
  }
  red[cg][t & 31] = p;
  __syncthreads();
  if (cg == 0 && o < Co) {
    float s = red[0][t] + red[1][t] + red[2][t] + red[3][t] + red[4][t] + red[5][t] + red[6][t] +
              red[7][t];
    out[(size_t)b * Co + o] = s + bias[o];
  }
}

__global__ void lat_bn_kernel(const float* __restrict__ latp, const float* __restrict__ lg,
                              const float* __restrict__ lbe, float* __restrict__ lat) {
  int o = blockIdx.x * 256 + threadIdx.x;
  float v[8];
  double s = 0.0, q = 0.0;
  for (int b = 0; b < 8; b++) {
    v[b] = latp[b * 1024 + o];
    s += (double)v[b];
    q += (double)v[b] * (double)v[b];
  }
  double mean = s * 0.125;
  double var = q * 0.125 - mean * mean;
  double r = 1.0 / sqrt(var + 1e-5);
  double gd = (double)lg[o], bd = (double)lbe[o];
  for (int b = 0; b < 8; b++) {
    float z = (float)(((double)v[b] - mean) * r * gd + bd);
    lat[b * 1024 + o] = fmaxf(z, 0.f);
  }
}

// z1[b][o][p] = w0[o]*rg0[b][p] + w1[o]*rg1[b][p] + u[b][o]
__global__ void dec1_z_kernel(const float* __restrict__ rg, const float* __restrict__ dW1t,
                              const float* __restrict__ u, float* __restrict__ z1) {
  int bo = blockIdx.x;
  int b = bo / 1026;
  int o = bo - b * 1026;
  int t = threadIdx.x;
  float w0 = dW1t[o], w1 = dW1t[1026 + o], ub = u[bo];
  const float4* r0 = (const float4*)(rg + (size_t)b * 2 * NP);
  const float4* r1 = (const float4*)(rg + (size_t)b * 2 * NP + NP);
  float4* zr = (float4*)(z1 + (size_t)bo * NP);
  for (int i = t; i < NP / 4; i += 256) {
    float4 a = r0[i], c = r1[i], rr;
    rr.x = fmaf(w0, a.x, fmaf(w1, c.x, ub));
    rr.y = fmaf(w0, a.y, fmaf(w1, c.y, ub));
    rr.z = fmaf(w0, a.z, fmaf(w1, c.z, ub));
    rr.w = fmaf(w0, a.w, fmaf(w1, c.w, ub));
    zr[i] = rr;
  }
}

// per-channel stats over (b,p) of z [B][C][P] -> scale/shift (double accum)
__global__ void dstats_kernel(const float* __restrict__ z, int C, const float* __restrict__ g,
                              const float* __restrict__ be, float* __restrict__ scale,
                              float* __restrict__ shift) {
  int o = blockIdx.x, t = threadIdx.x;
  double s = 0.0, q = 0.0;
  for (int b = 0; b < 8; b++) {
    const float4* row = (const float4*)(z + ((size_t)b * C + o) * NP);
    for (int i = t; i < NP / 4; i += 256) {
      float4 v = row[i];
      s += (double)v.x + (double)v.y + (double)v.z + (double)v.w;
      q += (double)v.x * v.x + (double)v.y * v.y + (double)v.z * v.z + (double)v.w * v.w;
    }
  }
  __shared__ double rs[256], rq[256];
  rs[t] = s; rq[t] = q;
  __syncthreads();
  for (int st = 128; st; st >>= 1) {
    if (t < st) { rs[t] += rs[t + st]; rq[t] += rq[t + st]; }
    __syncthreads();
  }
  if (t == 0) {
    double inv = 1.0 / (8.0 * NP);
    double mean = rs[0] * inv;
    double var = rq[0] * inv - mean * mean;
    double r = 1.0 / sqrt(var + 1e-5);
    double sc = (double)g[o] * r;
    scale[o] = (float)sc;
    shift[o] = (float)((double)be[o] - mean * sc);
  }
}

// ---------------- decoder GEMM (64x128 tile, KSTEP=32, XCD-swizzled) ----------------
template <int NMT>
__global__ __launch_bounds__(256, 2) void dec_gemm64s_kernel(
    const float* __restrict__ zin, const float* __restrict__ Wt, int ldA,
    const float* __restrict__ bias, const float* __restrict__ scale,
    const float* __restrict__ shift, float* __restrict__ zout, int Ci, int Co) {
  __shared__ float sA[32][64];   // [c][m]
  __shared__ float sB[32][128];  // [c][p]
  int bid = blockIdx.x;
  int gl = bid & 7;
  int q = bid >> 3;
  int gh = q / NMT;
  int mt = q - gh * NMT;
  int g = gl + (gh << 3);  // in [0, 128)
  int pt = g & 15;
  int b = g >> 4;
  int m0 = mt * 64, p0 = pt * 128;
  int t = threadIdx.x;
  int lr = t >> 4, lcA = (t & 15) * 4, lcB = (t & 15) * 8;
  int tx = t & 15, ty = t >> 4;
  int numK = (Ci + 31) >> 5;
  float acc[4][8] = {};
  float rA[8], rB[16];

  auto gloadhalf = [&](int c, float* ra, float* rb) {
#pragma unroll
    for (int j = 0; j < 4; j++) ra[j] = 0.f;
#pragma unroll
    for (int j = 0; j < 8; j++) rb[j] = 0.f;
    if (c < Ci) {
      int mb = m0 + lcA;
      if (mb + 4 <= Co) {
        float4 a0 = *(const float4*)&Wt[(size_t)c * ldA + mb];
        ra[0] = a0.x; ra[1] = a0.y; ra[2] = a0.z; ra[3] = a0.w;
      } else {
#pragma unroll
        for (int j = 0; j < 4; j++)
          if (mb + j < Co) ra[j] = Wt[(size_t)c * ldA + mb + j];
      }
      float sc = scale[c], sh = shift[c];
      const float* src = &zin[((size_t)b * Ci + c) * NP + p0 + lcB];
      float4 z0 = *(const float4*)src;
      float4 z1 = *(const float4*)(src + 4);
      rb[0] = fmaxf(fmaf(sc, z0.x, sh), 0.f);
      rb[1] = fmaxf(fmaf(sc, z0.y, sh), 0.f);
      rb[2] = fmaxf(fmaf(sc, z0.z, sh), 0.f);
      rb[3] = fmaxf(fmaf(sc, z0.w, sh), 0.f);
      rb[4] = fmaxf(fmaf(sc, z1.x, sh), 0.f);
      rb[5] = fmaxf(fmaf(sc, z1.y, sh), 0.f);
      rb[6] = fmaxf(fmaf(sc, z1.z, sh), 0.f);
      rb[7] = fmaxf(fmaf(sc, z1.w, sh), 0.f);
    }
  };
  auto gload = [&](int kt) {
    gloadhalf(kt * 32 + lr, rA, rB);
    gloadhalf(kt * 32 + 16 + lr, rA + 4, rB + 8);
  };
  auto ldswrite = [&]() {
    float4 v0;
    v0.x = rA[0]; v0.y = rA[1]; v0.z = rA[2]; v0.w = rA[3];
    *(float4*)&sA[lr][lcA] = v0;
    v0.x = rA[4]; v0.y = rA[5]; v0.z = rA[6]; v0.w = rA[7];
    *(float4*)&sA[16 + lr][lcA] = v0;
    float4 w0, w1;
    w0.x = rB[0]; w0.y = rB[1]; w0.z = rB[2]; w0.w = rB[3];
    w1.x = rB[4]; w1.y = rB[5]; w1.z = rB[6]; w1.w = rB[7];
    *(float4*)&sB[lr][lcB] = w0;
    *(float4*)&sB[lr][lcB + 4] = w1;
    w0.x = rB[8]; w0.y = rB[9]; w0.z = rB[10]; w0.w = rB[11];
    w1.x = rB[12]; w1.y = rB[13]; w1.z = rB[14]; w1.w = rB[15];
    *(float4*)&sB[16 + lr][lcB] = w0;
    *(float4*)&sB[16 + lr][lcB + 4] = w1;
  };

  gload(0);
  for (int kt = 0; kt < numK; kt++) {
    __syncthreads();
    ldswrite();
    __syncthreads();
    if (kt + 1 < numK) gload(kt + 1);
#pragma unroll
    for (int c = 0; c < 32; c++) {
      float4 a0 = *(const float4*)&sA[c][ty * 4];
      float4 b0 = *(const float4*)&sB[c][tx * 4];
      float4 b1 = *(const float4*)&sB[c][64 + tx * 4];
      float av[4] = {a0.x, a0.y, a0.z, a0.w};
      float bv[8] = {b0.x, b0.y, b0.z, b0.w, b1.x, b1.y, b1.z, b1.w};
#pragma unroll
      for (int i = 0; i < 4; i++)
#pragma unroll
        for (int j = 0; j < 8; j++) acc[i][j] = fmaf(av[i], bv[j], acc[i][j]);
    }
  }
#pragma unroll
  for (int i = 0; i < 4; i++) {
    int m = m0 + ty * 4 + i;
    if (m < Co) {
      float bv = bias[m];
      float* dst = &zout[((size_t)b * Co + m) * NP + p0];
      float4 q0, q1;
      q0.x = acc[i][0] + bv; q0.y = acc[i][1] + bv;
      q0.z = acc[i][2] + bv; q0.w = acc[i][3] + bv;
      q1.x = acc[i][4] + bv; q1.y = acc[i][5] + bv;
      q1.z = acc[i][6] + bv; q1.w = acc[i][7] + bv;
      *(float4*)&dst[tx * 4] = q0;
      *(float4*)&dst[64 + tx * 4] = q1;
    }
  }
}

// ---------------- final layer (c-split, 256 blocks) ----------------
__global__ void dec_final_kernel(const float* __restrict__ z3, const float* __restrict__ dW4,
                                 const float* __restrict__ db4, const float* __restrict__ scale,
                                 const float* __restrict__ shift, float* __restrict__ out) {
  __shared__ float w4[3 * 256];
  __shared__ float sc[256], sh[256];
  __shared__ float red[4][64][3];
  int b = blockIdx.x, pc = blockIdx.y, t = threadIdx.x;
  for (int e = t; e < 768; e += 256) w4[e] = dW4[e];
  sc[t] = scale[t];
  sh[t] = shift[t];
  __syncthreads();
  int tp = t & 63, tc = t >> 6;
  int p = pc * 64 + tp;
  float a0 = 0.f, a1 = 0.f, a2 = 0.f;
  for (int c = tc * 64; c < tc * 64 + 64; c++) {
    float hv = fmaxf(fmaf(sc[c], z3[((size_t)(b * 256 + c)) * NP + p], sh[c]), 0.f);
    a0 = fmaf(w4[c], hv, a0);
    a1 = fmaf(w4[256 + c], hv, a1);
    a2 = fmaf(w4[512 + c], hv, a2);
  }
  red[tc][tp][0] = a0;
  red[tc][tp][1] = a1;
  red[tc][tp][2] = a2;
  __syncthreads();
  if (tc == 0) {
    a0 = red[0][tp][0] + red[1][tp][0] + red[2][tp][0] + red[3][tp][0];
    a1 = red[0][tp][1] + red[1][tp][1] + red[2][tp][1] + red[3][tp][1];
    a2 = red[0][tp][2] + red[1][tp][2] + red[2][tp][2] + red[3][tp][2];
    out[((size_t)b * 3 + 0) * NP + p] = tanhf(a0 + db4[0]);
    out[((size_t)b * 3 + 1) * NP + p] = tanhf(a1 + db4[1]);
    out[((size_t)b * 3 + 2) * NP + p] = tanhf(a2 + db4[2]);
  }
}

// ---------------- host ----------------

extern "C" void kernel_launch(void* const* d_in, const int* in_sizes, int n_in, void* d_out,
                              int out_size, void* d_ws, size_t ws_size, hipStream_t stream) {
  const float* x = (const float*)d_in[0];
  const float* rg = (const float*)d_in[1];
  const float* W1 = (const float*)d_in[2];
  const float* b1 = (const float*)d_in[3];
  const float* g1 = (const float*)d_in[4];
  const float* be1 = (const float*)d_in[5];
  const float* W2 = (const float*)d_in[6];
  const float* b2 = (const float*)d_in[7];
  const float* g2 = (const float*)d_in[8];
  const float* be2 = (const float*)d_in[9];
  const float* W3 = (const float*)d_in[10];
  const float* b3 = (const float*)d_in[11];
  const float* g3 = (const float*)d_in[12];
  const float* be3 = (const float*)d_in[13];
  const float* W4 = (const float*)d_in[14];
  const float* b4 = (const float*)d_in[15];
  const float* g4 = (const float*)d_in[16];
  const float* be4 = (const float*)d_in[17];
  const float* W5 = (const float*)d_in[18];
  const float* b5 = (const float*)d_in[19];
  const float* g5 = (const float*)d_in[20];
  const float* be5 = (const float*)d_in[21];
  const float* lW = (const float*)d_in[22];
  const float* lb = (const float*)d_in[23];
  const float* lg = (const float*)d_in[24];
  const float* lbe = (const float*)d_in[25];
  const float* dW1 = (const float*)d_in[26];
  const float* db1 = (const float*)d_in[27];
  const float* dg1 = (const float*)d_in[28];
  const float* dbe1 = (const float*)d_in[29];
  const float* dW2 = (const float*)d_in[30];
  const float* db2 = (const float*)d_in[31];
  const float* dg2 = (const float*)d_in[32];
  const float* dbe2 = (const float*)d_in[33];
  const float* dW3 = (const float*)d_in[34];
  const float* db3 = (const float*)d_in[35];
  const float* dg3 = (const float*)d_in[36];
  const float* dbe3 = (const float*)d_in[37];
  const float* dW4 = (const float*)d_in[38];
  const float* db4 = (const float*)d_in[39];
  float* out = (float*)d_out;

  float* ws = (float*)d_ws;
  size_t off = 0;
  auto alloc = [&](size_t n) {
    size_t r = off;
    off += (n + 255) & ~(size_t)255;
    return r;
  };
  size_t f_pts = alloc((size_t)NB * NN * 3);
  // UnionA: cat + idx + zmax + zmin + psumf + psqf ; overlaid later by z2
  size_t f_uA = alloc(13959168);
  size_t f_cat = f_uA;
  size_t f_idx = f_cat + 5242880;
  size_t f_zmax = f_idx + 327680;
  size_t f_zmin = f_zmax + 2097152;
  size_t f_psum = f_zmin + 2097152;
  size_t f_psq = f_psum + 2097152;
  size_t f_z2 = f_uA;
  // UnionB: P (<=4.2M) -> z5 -> z1
  size_t f_uB = alloc(16809984);
  size_t f_z5 = f_uB, f_z1 = f_uB;
  float* P = ws + f_uB;
  // UnionC: W5 stats partials (doubles+floats) -> z3
  size_t f_uC = alloc(4194304);
  double* ps5_d = (double*)(ws + f_uC);  // 262,144 doubles
  double* pq5_d = ps5_d + 262144;        // 262,144 doubles
  size_t f_pM5 = f_uC + 2097152;
  size_t f_pm5 = f_pM5 + 262144;
  size_t f_z3 = f_uC;
  size_t f_weff = alloc(256 * 64);
  size_t f_W5t = alloc(320 * 1024);
  size_t f_lWt = alloc(1024 * 1024);
  size_t f_dW1t = alloc((size_t)1026 * 1026);
  size_t f_dW2t = alloc((size_t)1026 * 516);  // padded ld=516 for alignment
  size_t f_dW3t = alloc(513 * 256);
  size_t f_scale = alloc(2048);
  size_t f_shift = alloc(2048);
  size_t f_glob = alloc(8 * 1024);
  size_t f_latp = alloc(8 * 1024);
  size_t f_lat = alloc(8 * 1024);
  size_t f_u = alloc(8 * 1026);
  (void)ws_size;
  (void)in_sizes;
  (void)n_in;
  (void)out_size;

  float* cat = ws + f_cat;
  int* idxp = (int*)(ws + f_idx);
  float* zmax = ws + f_zmax;
  float* zmin = ws + f_zmin;
  float* psumf = ws + f_psum;
  float* psqf = ws + f_psq;
  float* weff = ws + f_weff;
  float* scale = ws + f_scale;
  float* shift = ws + f_shift;
  const double invn_e = 1.0 / (double)(NB * NN * NK);

  // prep
  transpose_x_kernel<<<192, 256, 0, stream>>>(x, ws + f_pts);
  transpose_mat_ld<<<dim3(10, 32), 256, 0, stream>>>(W5, ws + f_W5t, 1024, 320, 1024);
  transpose_mat_ld<<<dim3(32, 32), 256, 0, stream>>>(lW, ws + f_lWt, 1024, 1024, 1024);
  transpose_mat_ld<<<dim3(33, 33), 256, 0, stream>>>(dW1, ws + f_dW1t, 1026, 1026, 1026);
  transpose_mat_ld<<<dim3(33, 17), 256, 0, stream>>>(dW2, ws + f_dW2t, 513, 1026, 516);
  transpose_mat_ld<<<dim3(17, 8), 256, 0, stream>>>(dW3, ws + f_dW3t, 256, 513, 256);

  // ---- edge layer 1 (pts, D=3 -> 64 @ cat[0:64)) ----
  knn3_fused_kernel<<<NB * NN / 4, 256, 0, stream>>>(ws + f_pts, idxp);
  weff_kernel<<<2, 256, 0, stream>>>(W1, 64, 3, weff);
  pgemm_kernel<128, 3><<<2048, 256, 0, stream>>>(ws + f_pts, 3, 0, weff, b1, P);
  combine_kernel<64><<<4096, 256, 0, stream>>>(P, idxp, zmax, zmin, psumf, psqf);
  edge_reduce_kernel<<<64, 256, 0, stream>>>(psumf, psqf, g1, be1, scale, shift, invn_e);
  edge_affine_kernel<<<NB * NN * 64 / 256, 256, 0, stream>>>(zmax, zmin, scale, shift, cat, 64, 0);
  // ---- edge layer 2 (cat[0:64) -> cat[64:128)) ----
  knn64_fused2_kernel<<<dim3(64, 8), 1024, 0, stream>>>(cat, 320, 0, idxp);
  weff_kernel<<<32, 256, 0, stream>>>(W2, 64, 64, weff);
  pgemm_kernel<128, 64><<<2048, 256, 0, stream>>>(cat, 320, 0, weff, b2, P);
  combine_kernel<64><<<4096, 256, 0, stream>>>(P, idxp, zmax, zmin, psumf, psqf);
  edge_reduce_kernel<<<64, 256, 0, stream>>>(psumf, psqf, g2, be2, scale, shift, invn_e);
  edge_affine_kernel<<<NB * NN * 64 / 256, 256, 0, stream>>>(zmax, zmin, scale, shift, cat, 64, 64);
  // ---- edge layer 3 (cat[64:128) -> cat[128:192)) ----
  knn64_fused2_kernel<<<dim3(64, 8), 1024, 0, stream>>>(cat, 320, 64, idxp);
  weff_kernel<<<32, 256, 0, stream>>>(W3, 64, 64, weff);
  pgemm_kernel<128, 64><<<2048, 256, 0, stream>>>(cat, 320, 64, weff, b3, P);
  combine_kernel<64><<<4096, 256, 0, stream>>>(P, idxp, zmax, zmin, psumf, psqf);
  edge_reduce_kernel<<<64, 256, 0, stream>>>(psumf, psqf, g3, be3, scale, shift, invn_e);
  edge_affine_kernel<<<NB * NN * 64 / 256, 256, 0, stream>>>(zmax, zmin, scale, shift, cat, 64, 128);
  // ---- edge layer 4 (cat[128:192) -> cat[192:320)) ----
  knn64_fused2_kernel<<<dim3(64, 8), 1024, 0, stream>>>(cat, 320, 128, idxp);
  weff_kernel<<<64, 256, 0, stream>>>(W4, 128, 64, weff);
  pgemm_kernel<256, 64><<<2048, 256, 0, stream>>>(cat, 320, 128, weff, b4, P);
  combine_kernel<128><<<8192, 256, 0, stream>>>(P, idxp, zmax, zmin, psumf, psqf);
  edge_reduce_kernel<<<128, 256, 0, stream>>>(psumf, psqf, g4, be4, scale, shift, invn_e);
  edge_affine_kernel<<<NB * NN * 128 / 256, 256, 0, stream>>>(zmax, zmin, scale, shift, cat, 128, 192);

  // ---- W5 GEMM + global max ----
  gemm5_64_kernel<<<dim3(256, 8), 256, 0, stream>>>(cat, ws + f_W5t, b5, ws + f_z5);
  stats5_kernel<<<256, 256, 0, stream>>>(ws + f_z5, ps5_d, pq5_d, ws + f_pM5, ws + f_pm5);
  reduce5_glob_kernel<<<4, 256, 0, stream>>>(ps5_d, pq5_d, ws + f_pM5, ws + f_pm5, g5, be5,
                                             ws + f_glob);
  // ---- latent ----
  fc_kernel<<<dim3(8, 32), 256, 0, stream>>>(ws + f_glob, ws + f_lWt, 1024, 0, lb, ws + f_latp,
                                             1024, 1024);
  lat_bn_kernel<<<4, 256, 0, stream>>>(ws + f_latp, lg, lbe, ws + f_lat);
  // ---- decoder ----
  fc_kernel<<<dim3(8, 33), 256, 0, stream>>>(ws + f_lat, ws + f_dW1t, 1026, 2, db1, ws + f_u, 1024,
                                             1026);
  dec1_z_kernel<<<8 * 1026, 256, 0, stream>>>(rg, ws + f_dW1t, ws + f_u, ws + f_z1);
  dstats_kernel<<<1026, 256, 0, stream>>>(ws + f_z1, 1026, dg1, dbe1, scale, shift);
  dec_gemm64s_kernel<9><<<9 * 128, 256, 0, stream>>>(ws + f_z1, ws + f_dW2t, 516, db2, scale,
                                                     shift, ws + f_z2, 1026, 513);
  dstats_kernel<<<513, 256, 0, stream>>>(ws + f_z2, 513, dg2, dbe2, scale, shift);
  dec_gemm64s_kernel<4><<<4 * 128, 256, 0, stream>>>(ws + f_z2, ws + f_dW3t, 256, db3, scale,
                                                     shift, ws + f_z3, 513, 256);
  dstats_kernel<<<256, 256, 0, stream>>>(ws + f_z3, 256, dg3, dbe3, scale, shift);
  dec_final_kernel<<<dim3(8, 32), 256, 0, stream>>>(ws + f_z3, dW4, db4, scale, shift, out);
}

// Round 19
// 1705.106 us; speedup vs baseline: 1.1843x; 1.0741x over previous
//
#include <hip/hip_runtime.h>
#include <math.h>

constexpr int NB = 8;      // batch
constexpr int NN = 2048;   // points
constexpr int NK = 20;     // knn
constexpr int NP = 2048;   // decoder points

// ---------------- utils ----------------

__global__ void transpose_x_kernel(const float* __restrict__ x, float* __restrict__ pts) {
  int gid = blockIdx.x * 256 + threadIdx.x;  // over B*N*3 outputs [b][n][c]
  if (gid >= NB * NN * 3) return;
  int c = gid % 3;
  int n = (gid / 3) % NN;
  int b = gid / (3 * NN);
  pts[gid] = x[(b * 3 + c) * NN + n];
}

// dst[c*ldd + r] = src[r*C + c]
__global__ void transpose_mat_ld(const float* __restrict__ src, float* __restrict__ dst, int R,
                                 int C, int ldd) {
  __shared__ float tile[32][33];
  int c0 = blockIdx.x * 32, r0 = blockIdx.y * 32;
  int tx = threadIdx.x & 31, ty = threadIdx.x >> 5;  // 32 x 8
  for (int i = ty; i < 32; i += 8) {
    int r = r0 + i, c = c0 + tx;
    tile[i][tx] = (r < R && c < C) ? src[(size_t)r * C + c] : 0.f;
  }
  __syncthreads();
  for (int i = ty; i < 32; i += 8) {
    int c = c0 + i, r = r0 + tx;
    if (r < R && c < C) dst[(size_t)c * ldd + r] = tile[tx][i];
  }
}

// ---------------- KNN layer 1 (D=3): fused dist + top-20 ----------------
__global__ void knn3_fused_kernel(const float* __restrict__ pts, int* __restrict__ idx) {
  __shared__ float sm[3][NN];  // [dim][col]
  int t = threadIdx.x;
  int l = t & 63, w = t >> 6;
  int gb = blockIdx.x;    // over B*NN/4
  int b = gb >> 9;        // 512 blocks per batch
  int n0 = (gb & 511) * 4;
  const float* base = pts + (size_t)b * NN * 3;
  for (int e = t; e < NN * 3; e += 256) {
    int col = e / 3, d = e - col * 3;
    sm[d][col] = base[e];
  }
  __syncthreads();
  int n = n0 + w;
  float c0 = sm[0][n], c1 = sm[1][n], c2 = sm[2][n];
  float v[32];
#pragma unroll
  for (int j = 0; j < 32; j++) {
    int col = j * 64 + l;
    float d0 = c0 - sm[0][col];
    float d1 = c1 - sm[1][col];
    float d2 = c2 - sm[2][col];
    float acc = 0.f;
    acc = fmaf(d0, d0, acc);
    acc = fmaf(d1, d1, acc);
    acc = fmaf(d2, d2, acc);
    v[j] = -acc;
  }
  int mykm = 0;
  for (int k = 0; k < NK; k++) {
    float bv = v[0];
    int bj = 0;
#pragma unroll
    for (int j = 1; j < 32; j++) {
      if (v[j] > bv) { bv = v[j]; bj = j; }
    }
    int gm = bj * 64 + l;
#pragma unroll
    for (int off = 32; off; off >>= 1) {
      float ov = __shfl_xor(bv, off, 64);
      int om = __shfl_xor(gm, off, 64);
      if (ov > bv || (ov == bv && om < gm)) { bv = ov; gm = om; }
    }
    if (l == k) mykm = gm;
    int jb = gm >> 6, lb = gm & 63;
#pragma unroll
    for (int j = 0; j < 32; j++)
      if (j == jb && l == lb) v[j] = -3e38f;
  }
  if (l < NK) idx[((size_t)(b * NN + n)) * NK + l] = mykm;
}

// ---------------- KNN D=64: fused dist + top-20, 2 centers/wave, 1024 thr ----------------
// 1024-thread block (16 waves) owns 32 center rows; wave w owns centers
// n0+2w, n0+2w+1. Features stream through LDS in 16 transposed 128-col tiles
// (conflict-free staging: colg = t&127 spans lanes). Per d: two conflict-free
// scalar reads (cols l, 64+l) amortized over 2 centers (4 fma). Distances
// bit-identical to the two-phase path (same fmaf chain, d ascending).
// Slot j of lane l holds col (j>>1)*128 + (j&1)*64 + l (ascending in j).
// launch_bounds(1024, 8): VGPR cap 64 (uses 48) -> 2 blocks/CU resident.
__global__ __launch_bounds__(1024, 8) void knn64_fused2_kernel(const float* __restrict__ h,
                                                               int ld, int coff,
                                                               int* __restrict__ idx) {
  __shared__ float sft[64][128];  // feature tile [dim][col_local]
  __shared__ float sctr[32][64];  // 32 center rows
  int t = threadIdx.x;
  int l = t & 63, w = t >> 6;  // wave 0..15
  int n0 = blockIdx.x * 32;
  int b = blockIdx.y;
  const float* rows = h + (size_t)b * NN * ld + coff;
  for (int e = t; e < 32 * 64; e += 1024) {
    int r = e >> 6, d = e & 63;
    sctr[r][d] = rows[(size_t)(n0 + r) * ld + d];
  }
  int colg = t & 127;        // 0..127 (spans lanes -> conflict-free writes)
  int dh = (t >> 7) * 8;     // dim offset, 8 groups x 8 dims
  float v[2][32];
#pragma unroll
  for (int ct = 0; ct < 16; ct++) {
    __syncthreads();
    {
      const float* src = &rows[(size_t)(ct * 128 + colg) * ld + dh];
      float4 f0 = *(const float4*)src;
      float4 f1 = *(const float4*)(src + 4);
      sft[dh + 0][colg] = f0.x;
      sft[dh + 1][colg] = f0.y;
      sft[dh + 2][colg] = f0.z;
      sft[dh + 3][colg] = f0.w;
      sft[dh + 4][colg] = f1.x;
      sft[dh + 5][colg] = f1.y;
      sft[dh + 6][colg] = f1.z;
      sft[dh + 7][colg] = f1.w;
    }
    __syncthreads();
    float a00 = 0.f, a01 = 0.f, a10 = 0.f, a11 = 0.f;
#pragma unroll 8
    for (int d = 0; d < 64; d++) {
      float f0 = sft[d][l];       // lane-stride 1 -> conflict-free
      float f1 = sft[d][64 + l];  // lane-stride 1 -> conflict-free
      float c0v = sctr[2 * w + 0][d];  // wave-uniform broadcast
      float c1v = sctr[2 * w + 1][d];
      float e;
      e = c0v - f0; a00 = fmaf(e, e, a00);
      e = c0v - f1; a01 = fmaf(e, e, a01);
      e = c1v - f0; a10 = fmaf(e, e, a10);
      e = c1v - f1; a11 = fmaf(e, e, a11);
    }
    v[0][2 * ct] = -a00; v[0][2 * ct + 1] = -a01;
    v[1][2 * ct] = -a10; v[1][2 * ct + 1] = -a11;
  }
#pragma unroll
  for (int ci = 0; ci < 2; ci++) {
    int mykm = 0;
    for (int k = 0; k < NK; k++) {
      float bv = v[ci][0];
      int bj = 0;
#pragma unroll
      for (int j = 1; j < 32; j++) {
        if (v[ci][j] > bv) { bv = v[ci][j]; bj = j; }  // strict >: smallest col in-lane
      }
      int gm = ((bj >> 1) << 7) + ((bj & 1) << 6) + l;
#pragma unroll
      for (int off = 32; off; off >>= 1) {
        float ov = __shfl_xor(bv, off, 64);
        int om = __shfl_xor(gm, off, 64);
        if (ov > bv || (ov == bv && om < gm)) { bv = ov; gm = om; }
      }
      if (l == k) mykm = gm;
      int jb = ((gm >> 7) << 1) + ((gm >> 6) & 1);
      int lb = gm & 63;
#pragma unroll
      for (int j = 0; j < 32; j++)
        if (j == jb && l == lb) v[ci][j] = -3e38f;
    }
    if (l < NK) idx[((size_t)(b * NN + n0 + 2 * w + ci)) * NK + l] = mykm;
  }
}

// ---------------- Edge conv factorized: Weff, pgemm, combine ----------------
__global__ void weff_kernel(const float* __restrict__ W, int O, int D, float* __restrict__ Weff) {
  int i = blockIdx.x * 256 + threadIdx.x;  // over 2O*D
  if (i >= 2 * O * D) return;
  int o = i / D, d = i - o * D;
  float v;
  if (o < O) v = W[(size_t)o * 2 * D + d] - W[(size_t)o * 2 * D + D + d];
  else v = W[(size_t)(o - O) * 2 * D + D + d];
  Weff[i] = v;
}

// P[n][0..O) = bias + Weff[0..O) . h[n]; P[n][O..2O) = Weff[O..) . h[n]
template <int M2, int D>
__global__ __launch_bounds__(256, 4) void pgemm_kernel(const float* __restrict__ h, int ld,
                                                       int coff, const float* __restrict__ Weff,
                                                       const float* __restrict__ bias,
                                                       float* __restrict__ P) {
  constexpr int O = M2 / 2;
  constexpr int GRP = 256 / M2;  // 2 or 1
  constexpr int NR = 8 / GRP;    // 4 or 8
  __shared__ float sh[8][D == 3 ? 4 : 68];
  int t = threadIdx.x;
  int n0 = blockIdx.x * 8;
  const float* base = h + coff;
  if constexpr (D == 64) {
    if (t < 128) {
      int r = t >> 4, q = (t & 15) * 4;
      *(float4*)&sh[r][q] = *(const float4*)&base[(size_t)(n0 + r) * ld + q];
    }
  } else {
    if (t < 24) {
      int r = t / 3, c = t - r * 3;
      sh[r][c] = base[(size_t)(n0 + r) * ld + c];
    }
  }
  __syncthreads();
  int o = t % M2;
  int gi = t / M2;
  float acc[NR];
  float bz = (o < O) ? bias[o] : 0.f;
#pragma unroll
  for (int j = 0; j < NR; j++) acc[j] = bz;
  const float* wr = Weff + (size_t)o * D;
  if constexpr (D == 64) {
#pragma unroll
    for (int d4 = 0; d4 < 16; d4++) {
      float4 w4 = *(const float4*)&wr[d4 * 4];
#pragma unroll
      for (int j = 0; j < NR; j++) {
        float4 e4 = *(const float4*)&sh[gi * NR + j][d4 * 4];
        acc[j] = fmaf(w4.x, e4.x, acc[j]);
        acc[j] = fmaf(w4.y, e4.y, acc[j]);
        acc[j] = fmaf(w4.z, e4.z, acc[j]);
        acc[j] = fmaf(w4.w, e4.w, acc[j]);
      }
    }
  } else {
    float w0 = wr[0], w1 = wr[1], w2 = wr[2];
#pragma unroll
    for (int j = 0; j < NR; j++) {
      int r = gi * NR + j;
      acc[j] = fmaf(w0, sh[r][0], fmaf(w1, sh[r][1], fmaf(w2, sh[r][2], acc[j])));
    }
  }
#pragma unroll
  for (int j = 0; j < NR; j++)
    P[(size_t)(n0 + gi * NR + j) * M2 + o] = acc[j];
}

// z[n,k,o] = relu(P1[n][o] + P2[idx[n,k]][o]); track max/min over k + f32 sum/sumsq
template <int O>
__global__ __launch_bounds__(256, 8) void combine_kernel(const float* __restrict__ P,
                                                         const int* __restrict__ idx,
                                                         float* __restrict__ zmax,
                                                         float* __restrict__ zmin,
                                                         float* __restrict__ psum,
                                                         float* __restrict__ psq) {
  constexpr int CPB = 256 / O;
  constexpr int M2 = 2 * O;
  __shared__ int sidx[CPB * NK];
  int t = threadIdx.x;
  int bn0 = blockIdx.x * CPB;
  if (t < CPB * NK) sidx[t] = idx[(size_t)bn0 * NK + t];
  __syncthreads();
  int g = t / O, o = t % O;
  int bn = bn0 + g;
  int b = bn >> 11;
  float p1 = P[(size_t)bn * M2 + o];
  const float* P2 = P + (size_t)b * NN * M2 + O + o;
  float s = 0.f, sq = 0.f, mx = -3e38f, mn = 3e38f;
#pragma unroll
  for (int k = 0; k < NK; k++) {
    int nb = sidx[g * NK + k];
    float z = fmaxf(p1 + P2[(size_t)nb * M2], 0.f);
    s += z;
    sq = fmaf(z, z, sq);
    mx = fmaxf(mx, z);
    mn = fminf(mn, z);
  }
  zmax[(size_t)bn * O + o] = mx;
  zmin[(size_t)bn * O + o] = mn;
  psum[(size_t)o * (NB * NN) + bn] = s;
  psq[(size_t)o * (NB * NN) + bn] = sq;
}

__global__ void edge_reduce_kernel(const float* __restrict__ psum, const float* __restrict__ psq,
                                   const float* __restrict__ g, const float* __restrict__ be,
                                   float* __restrict__ scale, float* __restrict__ shift,
                                   double inv_n) {
  int o = blockIdx.x, t = threadIdx.x;
  double s = 0.0, q = 0.0;
  const float* ps = psum + (size_t)o * (NB * NN);
  const float* pq = psq + (size_t)o * (NB * NN);
  for (int i = t; i < NB * NN; i += 256) { s += (double)ps[i]; q += (double)pq[i]; }
  __shared__ double rs[256], rq[256];
  rs[t] = s; rq[t] = q;
  __syncthreads();
  for (int st = 128; st; st >>= 1) {
    if (t < st) { rs[t] += rs[t + st]; rq[t] += rq[t + st]; }
    __syncthreads();
  }
  if (t == 0) {
    double mean = rs[0] * inv_n;
    double var = rq[0] * inv_n - mean * mean;
    double r = 1.0 / sqrt(var + 1e-5);
    double sc = (double)g[o] * r;
    scale[o] = (float)sc;
    shift[o] = (float)((double)be[o] - mean * sc);
  }
}

__global__ void edge_affine_kernel(const float* __restrict__ zmax, const float* __restrict__ zmin,
                                   const float* __restrict__ scale, const float* __restrict__ shift,
                                   float* __restrict__ cat, int O, int coff_out) {
  int gid = blockIdx.x * 256 + threadIdx.x;  // over B*N*O
  int o = gid % O;
  int bn = gid / O;
  float sc = scale[o];
  float v = (sc >= 0.f) ? zmax[gid] : zmin[gid];
  cat[(size_t)bn * 320 + coff_out + o] = fmaf(sc, v, shift[o]);
}

// ---------------- W5 GEMM (64x128 tile, 4x8/thread, KSTEP=32) ----------------
__global__ __launch_bounds__(256, 4) void gemm5_64_kernel(const float* __restrict__ cat,
                                                          const float* __restrict__ W5t,
                                                          const float* __restrict__ b5,
                                                          float* __restrict__ z5) {
  __shared__ float sA[32][64];   // [c][row]
  __shared__ float sB[32][128];  // [c][m]
  int t = threadIdx.x;
  int r0 = blockIdx.x * 64, m0 = blockIdx.y * 128;
  int arow = t & 63, ach = (t >> 6) * 8;   // A: row, 8 c's
  int blr = t >> 4, blc = (t & 15) * 8;    // B: c in [0,16), 8 m's
  int tx = t & 15, ty = t >> 4;
  float acc[4][8] = {};
  float rA[8], rB[16];

  auto gload = [&](int c0) {
    const float* pa = &cat[(size_t)(r0 + arow) * 320 + c0 + ach];
    float4 a0 = *(const float4*)pa;
    float4 a1 = *(const float4*)(pa + 4);
    rA[0] = a0.x; rA[1] = a0.y; rA[2] = a0.z; rA[3] = a0.w;
    rA[4] = a1.x; rA[5] = a1.y; rA[6] = a1.z; rA[7] = a1.w;
    const float* pb = &W5t[(size_t)(c0 + blr) * 1024 + m0 + blc];
    float4 b0 = *(const float4*)pb;
    float4 b1 = *(const float4*)(pb + 4);
    rB[0] = b0.x; rB[1] = b0.y; rB[2] = b0.z; rB[3] = b0.w;
    rB[4] = b1.x; rB[5] = b1.y; rB[6] = b1.z; rB[7] = b1.w;
    const float* pb2 = &W5t[(size_t)(c0 + 16 + blr) * 1024 + m0 + blc];
    float4 c4 = *(const float4*)pb2;
    float4 c5 = *(const float4*)(pb2 + 4);
    rB[8] = c4.x; rB[9] = c4.y; rB[10] = c4.z; rB[11] = c4.w;
    rB[12] = c5.x; rB[13] = c5.y; rB[14] = c5.z; rB[15] = c5.w;
  };
  auto ldswrite = [&]() {
#pragma unroll
    for (int j = 0; j < 8; j++) sA[ach + j][arow] = rA[j];
    float4 w0, w1;
    w0.x = rB[0]; w0.y = rB[1]; w0.z = rB[2]; w0.w = rB[3];
    w1.x = rB[4]; w1.y = rB[5]; w1.z = rB[6]; w1.w = rB[7];
    *(float4*)&sB[blr][blc] = w0;
    *(float4*)&sB[blr][blc + 4] = w1;
    w0.x = rB[8]; w0.y = rB[9]; w0.z = rB[10]; w0.w = rB[11];
    w1.x = rB[12]; w1.y = rB[13]; w1.z = rB[14]; w1.w = rB[15];
    *(float4*)&sB[16 + blr][blc] = w0;
    *(float4*)&sB[16 + blr][blc + 4] = w1;
  };

  gload(0);
  for (int kt = 0; kt < 10; kt++) {
    __syncthreads();
    ldswrite();
    __syncthreads();
    if (kt + 1 < 10) gload((kt + 1) * 32);
#pragma unroll
    for (int c = 0; c < 32; c++) {
      float4 a0 = *(const float4*)&sA[c][ty * 4];
      float4 b0 = *(const float4*)&sB[c][tx * 4];
      float4 b1 = *(const float4*)&sB[c][64 + tx * 4];
      float av[4] = {a0.x, a0.y, a0.z, a0.w};
      float bv[8] = {b0.x, b0.y, b0.z, b0.w, b1.x, b1.y, b1.z, b1.w};
#pragma unroll
      for (int i = 0; i < 4; i++)
#pragma unroll
        for (int j = 0; j < 8; j++) acc[i][j] = fmaf(av[i], bv[j], acc[i][j]);
    }
  }
  float bj[8];
#pragma unroll
  for (int j = 0; j < 8; j++)
    bj[j] = b5[m0 + (j < 4 ? tx * 4 + j : 64 + tx * 4 + (j - 4))];
#pragma unroll
  for (int i = 0; i < 4; i++) {
    int r = r0 + ty * 4 + i;
    float* dst = &z5[(size_t)r * 1024 + m0];
    float4 q0, q1;
    q0.x = fmaxf(acc[i][0] + bj[0], 0.f);
    q0.y = fmaxf(acc[i][1] + bj[1], 0.f);
    q0.z = fmaxf(acc[i][2] + bj[2], 0.f);
    q0.w = fmaxf(acc[i][3] + bj[3], 0.f);
    q1.x = fmaxf(acc[i][4] + bj[4], 0.f);
    q1.y = fmaxf(acc[i][5] + bj[5], 0.f);
    q1.z = fmaxf(acc[i][6] + bj[6], 0.f);
    q1.w = fmaxf(acc[i][7] + bj[7], 0.f);
    *(float4*)&dst[tx * 4] = q0;
    *(float4*)&dst[64 + tx * 4] = q1;
  }
}

__global__ void stats5_kernel(const float* __restrict__ z5, double* __restrict__ psum5,
                              double* __restrict__ psq5, float* __restrict__ pmax5,
                              float* __restrict__ pmin5) {
  int j = blockIdx.x, t = threadIdx.x;
  int row0 = j * 64;
  double s0 = 0, s1 = 0, s2 = 0, s3 = 0, q0 = 0, q1 = 0, q2 = 0, q3 = 0;
  float4 mx = {-3e38f, -3e38f, -3e38f, -3e38f}, mn = {3e38f, 3e38f, 3e38f, 3e38f};
  for (int r = 0; r < 64; r++) {
    float4 v = *(const float4*)&z5[(size_t)(row0 + r) * 1024 + t * 4];
    s0 += v.x; s1 += v.y; s2 += v.z; s3 += v.w;
    q0 += (double)v.x * v.x; q1 += (double)v.y * v.y;
    q2 += (double)v.z * v.z; q3 += (double)v.w * v.w;
    mx.x = fmaxf(mx.x, v.x); mx.y = fmaxf(mx.y, v.y); mx.z = fmaxf(mx.z, v.z); mx.w = fmaxf(mx.w, v.w);
    mn.x = fminf(mn.x, v.x); mn.y = fminf(mn.y, v.y); mn.z = fminf(mn.z, v.z); mn.w = fminf(mn.w, v.w);
  }
  size_t base = (size_t)j * 1024 + t * 4;
  psum5[base + 0] = s0; psum5[base + 1] = s1; psum5[base + 2] = s2; psum5[base + 3] = s3;
  psq5[base + 0] = q0; psq5[base + 1] = q1; psq5[base + 2] = q2; psq5[base + 3] = q3;
  *(float4*)&pmax5[base] = mx;
  *(float4*)&pmin5[base] = mn;
}

__global__ void reduce5_glob_kernel(const double* __restrict__ psum5, const double* __restrict__ psq5,
                                    const float* __restrict__ pmax5, const float* __restrict__ pmin5,
                                    const float* __restrict__ g5, const float* __restrict__ be5,
                                    float* __restrict__ glob) {
  int o = blockIdx.x * 256 + threadIdx.x;
  double s = 0.0, q = 0.0;
  for (int j = 0; j < 256; j++) {
    s += psum5[(size_t)j * 1024 + o];
    q += psq5[(size_t)j * 1024 + o];
  }
  double mean = s * (1.0 / 16384.0);
  double var = q * (1.0 / 16384.0) - mean * mean;
  double r = 1.0 / sqrt(var + 1e-5);
  double scd = (double)g5[o] * r;
  float sc = (float)scd;
  float sh = (float)((double)be5[o] - mean * scd);
  for (int b = 0; b < 8; b++) {
    float m;
    if (sc >= 0.f) {
      m = -3e38f;
      for (int jj = 0; jj < 32; jj++) m = fmaxf(m, pmax5[(size_t)(b * 32 + jj) * 1024 + o]);
    } else {
      m = 3e38f;
      for (int jj = 0; jj < 32; jj++) m = fminf(m, pmin5[(size_t)(b * 32 + jj) * 1024 + o]);
    }
    glob[b * 1024 + o] = fmaf(sc, m, sh);
  }
}

// ---------------- fully-connected helper (o-tiled, 8-way c-split) ----------------
__global__ void fc_kernel(const float* __restrict__ in, const float* __restrict__ Wt, int ld,
                          int coff, const float* __restrict__ bias, float* __restrict__ out,
                          int Ci, int Co) {
  __shared__ float sin_[1024];
  __shared__ float red[8][32];
  int b = blockIdx.x, t = threadIdx.x;
  for (int e = t; e < Ci; e += 256) sin_[e] = in[(size_t)b * Ci + e];
  __syncthreads();
  int o = blockIdx.y * 32 + (t & 31);
  int cg = t >> 5;
  int cn = Ci / 8;
  float p = 0.f;
  if (o < Co) {
    for (int c = cg * cn; c < (cg + 1) * cn; c++)
      p = fmaf(Wt[(size_t)(c + coff) * ld + o], sin_[c], p);
  }
  red[cg][t & 31] = p;
  __syncthreads();
  if (cg == 0 && o < Co) {
    float s = red[0][t] + red[1][t] + red[2][t] + red[3][t] + red[4][t] + red[5][t] + red[6][t] +
              red[7][t];
    out[(size_t)b * Co + o] = s + bias[o];
  }
}

__global__ void lat_bn_kernel(const float* __restrict__ latp, const float* __restrict__ lg,
                              const float* __restrict__ lbe, float* __restrict__ lat) {
  int o = blockIdx.x * 256 + threadIdx.x;
  float v[8];
  double s = 0.0, q = 0.0;
  for (int b = 0; b < 8; b++) {
    v[b] = latp[b * 1024 + o];
    s += (double)v[b];
    q += (double)v[b] * (double)v[b];
  }
  double mean = s * 0.125;
  double var = q * 0.125 - mean * mean;
  double r = 1.0 / sqrt(var + 1e-5);
  double gd = (double)lg[o], bd = (double)lbe[o];
  for (int b = 0; b < 8; b++) {
    float z = (float)(((double)v[b] - mean) * r * gd + bd);
    lat[b * 1024 + o] = fmaxf(z, 0.f);
  }
}

// z1[b][o][p] = w0[o]*rg0[b][p] + w1[o]*rg1[b][p] + u[b][o]
__global__ void dec1_z_kernel(const float* __restrict__ rg, const float* __restrict__ dW1t,
                              const float* __restrict__ u, float* __restrict__ z1) {
  int bo = blockIdx.x;
  int b = bo / 1026;
  int o = bo - b * 1026;
  int t = threadIdx.x;
  float w0 = dW1t[o], w1 = dW1t[1026 + o], ub = u[bo];
  const float4* r0 = (const float4*)(rg + (size_t)b * 2 * NP);
  const float4* r1 = (const float4*)(rg + (size_t)b * 2 * NP + NP);
  float4* zr = (float4*)(z1 + (size_t)bo * NP);
  for (int i = t; i < NP / 4; i += 256) {
    float4 a = r0[i], c = r1[i], rr;
    rr.x = fmaf(w0, a.x, fmaf(w1, c.x, ub));
    rr.y = fmaf(w0, a.y, fmaf(w1, c.y, ub));
    rr.z = fmaf(w0, a.z, fmaf(w1, c.z, ub));
    rr.w = fmaf(w0, a.w, fmaf(w1, c.w, ub));
    zr[i] = rr;
  }
}

// per-channel stats over (b,p) of z [B][C][P] -> scale/shift (double accum)
__global__ void dstats_kernel(const float* __restrict__ z, int C, const float* __restrict__ g,
                              const float* __restrict__ be, float* __restrict__ scale,
                              float* __restrict__ shift) {
  int o = blockIdx.x, t = threadIdx.x;
  double s = 0.0, q = 0.0;
  for (int b = 0; b < 8; b++) {
    const float4* row = (const float4*)(z + ((size_t)b * C + o) * NP);
    for (int i = t; i < NP / 4; i += 256) {
      float4 v = row[i];
      s += (double)v.x + (double)v.y + (double)v.z + (double)v.w;
      q += (double)v.x * v.x + (double)v.y * v.y + (double)v.z * v.z + (double)v.w * v.w;
    }
  }
  __shared__ double rs[256], rq[256];
  rs[t] = s; rq[t] = q;
  __syncthreads();
  for (int st = 128; st; st >>= 1) {
    if (t < st) { rs[t] += rs[t + st]; rq[t] += rq[t + st]; }
    __syncthreads();
  }
  if (t == 0) {
    double inv = 1.0 / (8.0 * NP);
    double mean = rs[0] * inv;
    double var = rq[0] * inv - mean * mean;
    double r = 1.0 / sqrt(var + 1e-5);
    double sc = (double)g[o] * r;
    scale[o] = (float)sc;
    shift[o] = (float)((double)be[o] - mean * sc);
  }
}

// ---------------- decoder GEMM (64x128 tile, KSTEP=32, XCD-swizzled) ----------------
// Flat grid of NMT*128 blocks; bid = gl + 8*(gh*NMT + mt) with group g = gl + 8*gh,
// g = p-tile + 16*b. All NMT same-panel blocks share bid%8 -> same XCD L2.
template <int NMT>
__global__ __launch_bounds__(256, 4) void dec_gemm64s_kernel(
    const float* __restrict__ zin, const float* __restrict__ Wt, int ldA,
    const float* __restrict__ bias, const float* __restrict__ scale,
    const float* __restrict__ shift, float* __restrict__ zout, int Ci, int Co) {
  __shared__ float sA[32][64];   // [c][m]
  __shared__ float sB[32][128];  // [c][p]
  int bid = blockIdx.x;
  int gl = bid & 7;
  int q = bid >> 3;
  int gh = q / NMT;
  int mt = q - gh * NMT;
  int g = gl + (gh << 3);  // in [0, 128)
  int pt = g & 15;
  int b = g >> 4;
  int m0 = mt * 64, p0 = pt * 128;
  int t = threadIdx.x;
  int lr = t >> 4, lcA = (t & 15) * 4, lcB = (t & 15) * 8;
  int tx = t & 15, ty = t >> 4;
  int numK = (Ci + 31) >> 5;
  float acc[4][8] = {};
  float rA[8], rB[16];

  auto gloadhalf = [&](int c, float* ra, float* rb) {
#pragma unroll
    for (int j = 0; j < 4; j++) ra[j] = 0.f;
#pragma unroll
    for (int j = 0; j < 8; j++) rb[j] = 0.f;
    if (c < Ci) {
      int mb = m0 + lcA;
      if (mb + 4 <= Co) {
        float4 a0 = *(const float4*)&Wt[(size_t)c * ldA + mb];
        ra[0] = a0.x; ra[1] = a0.y; ra[2] = a0.z; ra[3] = a0.w;
      } else {
#pragma unroll
        for (int j = 0; j < 4; j++)
          if (mb + j < Co) ra[j] = Wt[(size_t)c * ldA + mb + j];
      }
      float sc = scale[c], sh = shift[c];
      const float* src = &zin[((size_t)b * Ci + c) * NP + p0 + lcB];
      float4 z0 = *(const float4*)src;
      float4 z1 = *(const float4*)(src + 4);
      rb[0] = fmaxf(fmaf(sc, z0.x, sh), 0.f);
      rb[1] = fmaxf(fmaf(sc, z0.y, sh), 0.f);
      rb[2] = fmaxf(fmaf(sc, z0.z, sh), 0.f);
      rb[3] = fmaxf(fmaf(sc, z0.w, sh), 0.f);
      rb[4] = fmaxf(fmaf(sc, z1.x, sh), 0.f);
      rb[5] = fmaxf(fmaf(sc, z1.y, sh), 0.f);
      rb[6] = fmaxf(fmaf(sc, z1.z, sh), 0.f);
      rb[7] = fmaxf(fmaf(sc, z1.w, sh), 0.f);
    }
  };
  auto gload = [&](int kt) {
    gloadhalf(kt * 32 + lr, rA, rB);
    gloadhalf(kt * 32 + 16 + lr, rA + 4, rB + 8);
  };
  auto ldswrite = [&]() {
    float4 v0;
    v0.x = rA[0]; v0.y = rA[1]; v0.z = rA[2]; v0.w = rA[3];
    *(float4*)&sA[lr][lcA] = v0;
    v0.x = rA[4]; v0.y = rA[5]; v0.z = rA[6]; v0.w = rA[7];
    *(float4*)&sA[16 + lr][lcA] = v0;
    float4 w0, w1;
    w0.x = rB[0]; w0.y = rB[1]; w0.z = rB[2]; w0.w = rB[3];
    w1.x = rB[4]; w1.y = rB[5]; w1.z = rB[6]; w1.w = rB[7];
    *(float4*)&sB[lr][lcB] = w0;
    *(float4*)&sB[lr][lcB + 4] = w1;
    w0.x = rB[8]; w0.y = rB[9]; w0.z = rB[10]; w0.w = rB[11];
    w1.x = rB[12]; w1.y = rB[13]; w1.z = rB[14]; w1.w = rB[15];
    *(float4*)&sB[16 + lr][lcB] = w0;
    *(float4*)&sB[16 + lr][lcB + 4] = w1;
  };

  gload(0);
  for (int kt = 0; kt < numK; kt++) {
    __syncthreads();
    ldswrite();
    __syncthreads();
    if (kt + 1 < numK) gload(kt + 1);
#pragma unroll
    for (int c = 0; c < 32; c++) {
      float4 a0 = *(const float4*)&sA[c][ty * 4];
      float4 b0 = *(const float4*)&sB[c][tx * 4];
      float4 b1 = *(const float4*)&sB[c][64 + tx * 4];
      float av[4] = {a0.x, a0.y, a0.z, a0.w};
      float bv[8] = {b0.x, b0.y, b0.z, b0.w, b1.x, b1.y, b1.z, b1.w};
#pragma unroll
      for (int i = 0; i < 4; i++)
#pragma unroll
        for (int j = 0; j < 8; j++) acc[i][j] = fmaf(av[i], bv[j], acc[i][j]);
    }
  }
#pragma unroll
  for (int i = 0; i < 4; i++) {
    int m = m0 + ty * 4 + i;
    if (m < Co) {
      float bv = bias[m];
      float* dst = &zout[((size_t)b * Co + m) * NP + p0];
      float4 q0, q1;
      q0.x = acc[i][0] + bv; q0.y = acc[i][1] + bv;
      q0.z = acc[i][2] + bv; q0.w = acc[i][3] + bv;
      q1.x = acc[i][4] + bv; q1.y = acc[i][5] + bv;
      q1.z = acc[i][6] + bv; q1.w = acc[i][7] + bv;
      *(float4*)&dst[tx * 4] = q0;
      *(float4*)&dst[64 + tx * 4] = q1;
    }
  }
}

// ---------------- final layer (c-split, 256 blocks) ----------------
__global__ void dec_final_kernel(const float* __restrict__ z3, const float* __restrict__ dW4,
                                 const float* __restrict__ db4, const float* __restrict__ scale,
                                 const float* __restrict__ shift, float* __restrict__ out) {
  __shared__ float w4[3 * 256];
  __shared__ float sc[256], sh[256];
  __shared__ float red[4][64][3];
  int b = blockIdx.x, pc = blockIdx.y, t = threadIdx.x;
  for (int e = t; e < 768; e += 256) w4[e] = dW4[e];
  sc[t] = scale[t];
  sh[t] = shift[t];
  __syncthreads();
  int tp = t & 63, tc = t >> 6;
  int p = pc * 64 + tp;
  float a0 = 0.f, a1 = 0.f, a2 = 0.f;
  for (int c = tc * 64; c < tc * 64 + 64; c++) {
    float hv = fmaxf(fmaf(sc[c], z3[((size_t)(b * 256 + c)) * NP + p], sh[c]), 0.f);
    a0 = fmaf(w4[c], hv, a0);
    a1 = fmaf(w4[256 + c], hv, a1);
    a2 = fmaf(w4[512 + c], hv, a2);
  }
  red[tc][tp][0] = a0;
  red[tc][tp][1] = a1;
  red[tc][tp][2] = a2;
  __syncthreads();
  if (tc == 0) {
    a0 = red[0][tp][0] + red[1][tp][0] + red[2][tp][0] + red[3][tp][0];
    a1 = red[0][tp][1] + red[1][tp][1] + red[2][tp][1] + red[3][tp][1];
    a2 = red[0][tp][2] + red[1][tp][2] + red[2][tp][2] + red[3][tp][2];
    out[((size_t)b * 3 + 0) * NP + p] = tanhf(a0 + db4[0]);
    out[((size_t)b * 3 + 1) * NP + p] = tanhf(a1 + db4[1]);
    out[((size_t)b * 3 + 2) * NP + p] = tanhf(a2 + db4[2]);
  }
}

// ---------------- host ----------------

extern "C" void kernel_launch(void* const* d_in, const int* in_sizes, int n_in, void* d_out,
                              int out_size, void* d_ws, size_t ws_size, hipStream_t stream) {
  const float* x = (const float*)d_in[0];
  const float* rg = (const float*)d_in[1];
  const float* W1 = (const float*)d_in[2];
  const float* b1 = (const float*)d_in[3];
  const float* g1 = (const float*)d_in[4];
  const float* be1 = (const float*)d_in[5];
  const float* W2 = (const float*)d_in[6];
  const float* b2 = (const float*)d_in[7];
  const float* g2 = (const float*)d_in[8];
  const float* be2 = (const float*)d_in[9];
  const float* W3 = (const float*)d_in[10];
  const float* b3 = (const float*)d_in[11];
  const float* g3 = (const float*)d_in[12];
  const float* be3 = (const float*)d_in[13];
  const float* W4 = (const float*)d_in[14];
  const float* b4 = (const float*)d_in[15];
  const float* g4 = (const float*)d_in[16];
  const float* be4 = (const float*)d_in[17];
  const float* W5 = (const float*)d_in[18];
  const float* b5 = (const float*)d_in[19];
  const float* g5 = (const float*)d_in[20];
  const float* be5 = (const float*)d_in[21];
  const float* lW = (const float*)d_in[22];
  const float* lb = (const float*)d_in[23];
  const float* lg = (const float*)d_in[24];
  const float* lbe = (const float*)d_in[25];
  const float* dW1 = (const float*)d_in[26];
  const float* db1 = (const float*)d_in[27];
  const float* dg1 = (const float*)d_in[28];
  const float* dbe1 = (const float*)d_in[29];
  const float* dW2 = (const float*)d_in[30];
  const float* db2 = (const float*)d_in[31];
  const float* dg2 = (const float*)d_in[32];
  const float* dbe2 = (const float*)d_in[33];
  const float* dW3 = (const float*)d_in[34];
  const float* db3 = (const float*)d_in[35];
  const float* dg3 = (const float*)d_in[36];
  const float* dbe3 = (const float*)d_in[37];
  const float* dW4 = (const float*)d_in[38];
  const float* db4 = (const float*)d_in[39];
  float* out = (float*)d_out;

  float* ws = (float*)d_ws;
  size_t off = 0;
  auto alloc = [&](size_t n) {
    size_t r = off;
    off += (n + 255) & ~(size_t)255;
    return r;
  };
  size_t f_pts = alloc((size_t)NB * NN * 3);
  // UnionA: cat + idx + zmax + zmin + psumf + psqf ; overlaid later by z2
  size_t f_uA = alloc(13959168);
  size_t f_cat = f_uA;
  size_t f_idx = f_cat + 5242880;
  size_t f_zmax = f_idx + 327680;
  size_t f_zmin = f_zmax + 2097152;
  size_t f_psum = f_zmin + 2097152;
  size_t f_psq = f_psum + 2097152;
  size_t f_z2 = f_uA;
  // UnionB: P (<=4.2M) -> z5 -> z1
  size_t f_uB = alloc(16809984);
  size_t f_z5 = f_uB, f_z1 = f_uB;
  float* P = ws + f_uB;
  // UnionC: W5 stats partials (doubles+floats) -> z3
  size_t f_uC = alloc(4194304);
  double* ps5_d = (double*)(ws + f_uC);  // 262,144 doubles
  double* pq5_d = ps5_d + 262144;        // 262,144 doubles
  size_t f_pM5 = f_uC + 2097152;
  size_t f_pm5 = f_pM5 + 262144;
  size_t f_z3 = f_uC;
  size_t f_weff = alloc(256 * 64);
  size_t f_W5t = alloc(320 * 1024);
  size_t f_lWt = alloc(1024 * 1024);
  size_t f_dW1t = alloc((size_t)1026 * 1026);
  size_t f_dW2t = alloc((size_t)1026 * 516);  // padded ld=516 for alignment
  size_t f_dW3t = alloc(513 * 256);
  size_t f_scale = alloc(2048);
  size_t f_shift = alloc(2048);
  size_t f_glob = alloc(8 * 1024);
  size_t f_latp = alloc(8 * 1024);
  size_t f_lat = alloc(8 * 1024);
  size_t f_u = alloc(8 * 1026);
  (void)ws_size;
  (void)in_sizes;
  (void)n_in;
  (void)out_size;

  float* cat = ws + f_cat;
  int* idxp = (int*)(ws + f_idx);
  float* zmax = ws + f_zmax;
  float* zmin = ws + f_zmin;
  float* psumf = ws + f_psum;
  float* psqf = ws + f_psq;
  float* weff = ws + f_weff;
  float* scale = ws + f_scale;
  float* shift = ws + f_shift;
  const double invn_e = 1.0 / (double)(NB * NN * NK);

  // prep
  transpose_x_kernel<<<192, 256, 0, stream>>>(x, ws + f_pts);
  transpose_mat_ld<<<dim3(10, 32), 256, 0, stream>>>(W5, ws + f_W5t, 1024, 320, 1024);
  transpose_mat_ld<<<dim3(32, 32), 256, 0, stream>>>(lW, ws + f_lWt, 1024, 1024, 1024);
  transpose_mat_ld<<<dim3(33, 33), 256, 0, stream>>>(dW1, ws + f_dW1t, 1026, 1026, 1026);
  transpose_mat_ld<<<dim3(33, 17), 256, 0, stream>>>(dW2, ws + f_dW2t, 513, 1026, 516);
  transpose_mat_ld<<<dim3(17, 8), 256, 0, stream>>>(dW3, ws + f_dW3t, 256, 513, 256);

  // ---- edge layer 1 (pts, D=3 -> 64 @ cat[0:64)) ----
  knn3_fused_kernel<<<NB * NN / 4, 256, 0, stream>>>(ws + f_pts, idxp);
  weff_kernel<<<2, 256, 0, stream>>>(W1, 64, 3, weff);
  pgemm_kernel<128, 3><<<2048, 256, 0, stream>>>(ws + f_pts, 3, 0, weff, b1, P);
  combine_kernel<64><<<4096, 256, 0, stream>>>(P, idxp, zmax, zmin, psumf, psqf);
  edge_reduce_kernel<<<64, 256, 0, stream>>>(psumf, psqf, g1, be1, scale, shift, invn_e);
  edge_affine_kernel<<<NB * NN * 64 / 256, 256, 0, stream>>>(zmax, zmin, scale, shift, cat, 64, 0);
  // ---- edge layer 2 (cat[0:64) -> cat[64:128)) ----
  knn64_fused2_kernel<<<dim3(64, 8), 1024, 0, stream>>>(cat, 320, 0, idxp);
  weff_kernel<<<32, 256, 0, stream>>>(W2, 64, 64, weff);
  pgemm_kernel<128, 64><<<2048, 256, 0, stream>>>(cat, 320, 0, weff, b2, P);
  combine_kernel<64><<<4096, 256, 0, stream>>>(P, idxp, zmax, zmin, psumf, psqf);
  edge_reduce_kernel<<<64, 256, 0, stream>>>(psumf, psqf, g2, be2, scale, shift, invn_e);
  edge_affine_kernel<<<NB * NN * 64 / 256, 256, 0, stream>>>(zmax, zmin, scale, shift, cat, 64, 64);
  // ---- edge layer 3 (cat[64:128) -> cat[128:192)) ----
  knn64_fused2_kernel<<<dim3(64, 8), 1024, 0, stream>>>(cat, 320, 64, idxp);
  weff_kernel<<<32, 256, 0, stream>>>(W3, 64, 64, weff);
  pgemm_kernel<128, 64><<<2048, 256, 0, stream>>>(cat, 320, 64, weff, b3, P);
  combine_kernel<64><<<4096, 256, 0, stream>>>(P, idxp, zmax, zmin, psumf, psqf);
  edge_reduce_kernel<<<64, 256, 0, stream>>>(psumf, psqf, g3, be3, scale, shift, invn_e);
  edge_affine_kernel<<<NB * NN * 64 / 256, 256, 0, stream>>>(zmax, zmin, scale, shift, cat, 64, 128);
  // ---- edge layer 4 (cat[128:192) -> cat[192:320)) ----
  knn64_fused2_kernel<<<dim3(64, 8), 1024, 0, stream>>>(cat, 320, 128, idxp);
  weff_kernel<<<64, 256, 0, stream>>>(W4, 128, 64, weff);
  pgemm_kernel<256, 64><<<2048, 256, 0, stream>>>(cat, 320, 128, weff, b4, P);
  combine_kernel<128><<<8192, 256, 0, stream>>>(P, idxp, zmax, zmin, psumf, psqf);
  edge_reduce_kernel<<<128, 256, 0, stream>>>(psumf, psqf, g4, be4, scale, shift, invn_e);
  edge_affine_kernel<<<NB * NN * 128 / 256, 256, 0, stream>>>(zmax, zmin, scale, shift, cat, 128, 192);

  // ---- W5 GEMM + global max ----
  gemm5_64_kernel<<<dim3(256, 8), 256, 0, stream>>>(cat, ws + f_W5t, b5, ws + f_z5);
  stats5_kernel<<<256, 256, 0, stream>>>(ws + f_z5, ps5_d, pq5_d, ws + f_pM5, ws + f_pm5);
  reduce5_glob_kernel<<<4, 256, 0, stream>>>(ps5_d, pq5_d, ws + f_pM5, ws + f_pm5, g5, be5,
                                             ws + f_glob);
  // ---- latent ----
  fc_kernel<<<dim3(8, 32), 256, 0, stream>>>(ws + f_glob, ws + f_lWt, 1024, 0, lb, ws + f_latp,
                                             1024, 1024);
  lat_bn_kernel<<<4, 256, 0, stream>>>(ws + f_latp, lg, lbe, ws + f_lat);
  // ---- decoder ----
  fc_kernel<<<dim3(8, 33), 256, 0, stream>>>(ws + f_lat, ws + f_dW1t, 1026, 2, db1, ws + f_u, 1024,
                                             1026);
  dec1_z_kernel<<<8 * 1026, 256, 0, stream>>>(rg, ws + f_dW1t, ws + f_u, ws + f_z1);
  dstats_kernel<<<1026, 256, 0, stream>>>(ws + f_z1, 1026, dg1, dbe1, scale, shift);
  dec_gemm64s_kernel<9><<<9 * 128, 256, 0, stream>>>(ws + f_z1, ws + f_dW2t, 516, db2, scale,
                                                     shift, ws + f_z2, 1026, 513);
  dstats_kernel<<<513, 256, 0, stream>>>(ws + f_z2, 513, dg2, dbe2, scale, shift);
  dec_gemm64s_kernel<4><<<4 * 128, 256, 0, stream>>>(ws + f_z2, ws + f_dW3t, 256, db3, scale,
                                                     shift, ws + f_z3, 513, 256);
  dstats_kernel<<<256, 256, 0, stream>>>(ws + f_z3, 256, dg3, dbe3, scale, shift);
  dec_final_kernel<<<dim3(8, 32), 256, 0, stream>>>(ws + f_z3, dW4, db4, scale, shift, out);
}